// Round 1
// baseline (562.374 us; speedup 1.0000x reference)
//
#include <hip/hip_runtime.h>
#include <cstddef>

#define N_NODES 50000
#define N_EDGES 800000
#define D 128

#define TM 64
#define TKC 64
#define ASTRIDE 68   // 64 + 4 pad floats; row stride 272B = 16B-aligned

// ---------------- zero workspace ----------------
__global__ void zero_kernel(float4* __restrict__ ws, int n4) {
    int i = blockIdx.x * blockDim.x + threadIdx.x;
    if (i < n4) ws[i] = make_float4(0.f, 0.f, 0.f, 0.f);
}

// ---------------- edge aggregation (atomic scatter) ----------------
__launch_bounds__(256)
__global__ void aggregate_kernel(const float* __restrict__ feat,
                                 const int* __restrict__ src,
                                 const int* __restrict__ dst,
                                 float* __restrict__ summed,
                                 float* __restrict__ deg) {
    const int k = threadIdx.x & (D - 1);     // 0..127 feature
    const int half = threadIdx.x >> 7;       // 0 or 1: which edge of the pair
    const int estride = gridDim.x * 2;
    for (int e = blockIdx.x * 2 + half; e < N_EDGES; e += estride) {
        const int s = src[e];                // wave-uniform -> scalar load
        const int d = dst[e];
        atomicAdd(&summed[(size_t)d * D + k], feat[(size_t)s * D + k]);
        if (k == 0) atomicAdd(&deg[d], 1.0f);
    }
}

// ---------------- fused GEMM: out = feat@Wself^T + b + (summed/deg)@Wneigh^T ----------------
__launch_bounds__(256)
__global__ void gemm_kernel(const float* __restrict__ feat,
                            const float* __restrict__ Wself,
                            const float* __restrict__ Wneigh,
                            const float* __restrict__ bias,
                            const float* __restrict__ summed,
                            const float* __restrict__ deg,
                            float* __restrict__ out) {
    __shared__ __align__(16) float As[TM * ASTRIDE];
    __shared__ __align__(16) float Ws[D * ASTRIDE];

    const int tid = threadIdx.x;
    const int tx = tid & 15;   // output-feature group: j = tx + 16*r
    const int ty = tid >> 4;   // node group: n = row0 + ty*4 + i
    const int row0 = blockIdx.x * TM;

    float acc[4][8];
#pragma unroll
    for (int i = 0; i < 4; ++i)
#pragma unroll
        for (int r = 0; r < 8; ++r) acc[i][r] = 0.f;

#pragma unroll 1
    for (int phase = 0; phase < 2; ++phase) {
        const float* __restrict__ A = (phase == 0) ? feat : summed;
        const float* __restrict__ W = (phase == 0) ? Wself : Wneigh;
#pragma unroll 1
        for (int kb = 0; kb < D; kb += TKC) {
            __syncthreads();   // previous compute done before LDS overwrite
            // stage A tile: TM x TKC floats = 1024 float4, 4 per thread
#pragma unroll
            for (int i = 0; i < 4; ++i) {
                const int elem = tid + i * 256;
                const int arow = elem >> 4;   // 0..63
                const int c4   = elem & 15;   // 0..15
                const int grow = row0 + arow;
                float4 v = make_float4(0.f, 0.f, 0.f, 0.f);
                if (grow < N_NODES) {
                    v = *(const float4*)&A[(size_t)grow * D + kb + c4 * 4];
                    if (phase == 1) {
                        const float sc = 1.0f / fmaxf(deg[grow], 1.0f);
                        v.x *= sc; v.y *= sc; v.z *= sc; v.w *= sc;
                    }
                }
                *(float4*)&As[arow * ASTRIDE + c4 * 4] = v;
            }
            // stage W tile: D x TKC floats = 2048 float4, 8 per thread
#pragma unroll
            for (int i = 0; i < 8; ++i) {
                const int elem = tid + i * 256;
                const int wrow = elem >> 4;   // 0..127
                const int c4   = elem & 15;
                const float4 v = *(const float4*)&W[(size_t)wrow * D + kb + c4 * 4];
                *(float4*)&Ws[wrow * ASTRIDE + c4 * 4] = v;
            }
            __syncthreads();
            // compute: 4 nodes x 8 outputs per thread
#pragma unroll
            for (int k4 = 0; k4 < TKC / 4; ++k4) {
                float4 a[4];
#pragma unroll
                for (int i = 0; i < 4; ++i)
                    a[i] = *(const float4*)&As[(ty * 4 + i) * ASTRIDE + k4 * 4];
#pragma unroll
                for (int r = 0; r < 8; ++r) {
                    const float4 w = *(const float4*)&Ws[(tx + 16 * r) * ASTRIDE + k4 * 4];
#pragma unroll
                    for (int i = 0; i < 4; ++i)
                        acc[i][r] += a[i].x * w.x + a[i].y * w.y
                                   + a[i].z * w.z + a[i].w * w.w;
                }
            }
        }
    }

    float bv[8];
#pragma unroll
    for (int r = 0; r < 8; ++r) bv[r] = bias[tx + 16 * r];

#pragma unroll
    for (int i = 0; i < 4; ++i) {
        const int grow = row0 + ty * 4 + i;
        if (grow < N_NODES) {
#pragma unroll
            for (int r = 0; r < 8; ++r)
                out[(size_t)grow * D + tx + 16 * r] = acc[i][r] + bv[r];
        }
    }
}

extern "C" void kernel_launch(void* const* d_in, const int* in_sizes, int n_in,
                              void* d_out, int out_size, void* d_ws, size_t ws_size,
                              hipStream_t stream) {
    const float* feat  = (const float*)d_in[0];
    const float* Wn    = (const float*)d_in[1];  // W_neigh
    const float* Wsf   = (const float*)d_in[2];  // W_self
    const float* bself = (const float*)d_in[3];
    const int*   src   = (const int*)d_in[4];
    const int*   dst   = (const int*)d_in[5];
    float* out = (float*)d_out;

    float* summed = (float*)d_ws;                       // N_NODES * D floats
    float* deg    = summed + (size_t)N_NODES * D;       // N_NODES floats

    const int n4 = (N_NODES * D + N_NODES) / 4;         // 1,612,500 float4s
    zero_kernel<<<(n4 + 255) / 256, 256, 0, stream>>>((float4*)d_ws, n4);

    aggregate_kernel<<<4096, 256, 0, stream>>>(feat, src, dst, summed, deg);

    gemm_kernel<<<(N_NODES + TM - 1) / TM, 256, 0, stream>>>(
        feat, Wsf, Wn, bself, summed, deg, out);
}

// Round 2
// 347.475 us; speedup vs baseline: 1.6185x; 1.6185x over previous
//
#include <hip/hip_runtime.h>
#include <cstddef>

#define N_NODES 50000
#define N_EDGES 800000
#define D 128

#define TM 64
#define TKC 64
#define ASTRIDE 68   // 64 + 4 pad floats; row stride 272B = 16B-aligned

#define NB_SCAN ((N_NODES + 255) / 256)   // 196 blocks for the scan

// ---------------- zero degree counters ----------------
__global__ void zero_deg_kernel(int* __restrict__ deg_i) {
    int i = blockIdx.x * blockDim.x + threadIdx.x;
    if (i < N_NODES) deg_i[i] = 0;
}

// ---------------- per-dst degree count ----------------
__launch_bounds__(256)
__global__ void count_kernel(const int* __restrict__ dst, int* __restrict__ deg_i) {
    int e = blockIdx.x * blockDim.x + threadIdx.x;
    if (e < N_EDGES) atomicAdd(&deg_i[dst[e]], 1);
}

// ---------------- scan part a: per-block sums ----------------
__launch_bounds__(256)
__global__ void scan_a_kernel(const int* __restrict__ deg_i, int* __restrict__ blocksums) {
    __shared__ int s[256];
    const int t = threadIdx.x;
    const int i = blockIdx.x * 256 + t;
    s[t] = (i < N_NODES) ? deg_i[i] : 0;
    __syncthreads();
    for (int d = 128; d > 0; d >>= 1) {
        if (t < d) s[t] += s[t + d];
        __syncthreads();
    }
    if (t == 0) blocksums[blockIdx.x] = s[0];
}

// ---------------- scan part b: exclusive scan of block sums (1 block) ----------------
__global__ void scan_b_kernel(int* __restrict__ blocksums) {
    if (threadIdx.x == 0 && blockIdx.x == 0) {
        int run = 0;
        for (int b = 0; b < NB_SCAN; ++b) {
            int v = blocksums[b];
            blocksums[b] = run;
            run += v;
        }
    }
}

// ---------------- scan part c: per-block exclusive scan + base ----------------
__launch_bounds__(256)
__global__ void scan_c_kernel(const int* __restrict__ deg_i,
                              const int* __restrict__ blocksums,
                              int* __restrict__ off,
                              int* __restrict__ cursor) {
    __shared__ int s[256];
    const int t = threadIdx.x;
    const int i = blockIdx.x * 256 + t;
    const int c = (i < N_NODES) ? deg_i[i] : 0;
    s[t] = c;
    __syncthreads();
    for (int d = 1; d < 256; d <<= 1) {
        int v = 0;
        if (t >= d) v = s[t - d];
        __syncthreads();
        s[t] += v;
        __syncthreads();
    }
    if (i < N_NODES) {
        const int excl = s[t] - c + blocksums[blockIdx.x];
        off[i] = excl;
        cursor[i] = excl;
    }
}

// ---------------- scatter edges into CSR ----------------
__launch_bounds__(256)
__global__ void scatter_kernel(const int* __restrict__ src,
                               const int* __restrict__ dst,
                               int* __restrict__ cursor,
                               int* __restrict__ csr_src) {
    int e = blockIdx.x * blockDim.x + threadIdx.x;
    if (e < N_EDGES) {
        const int p = atomicAdd(&cursor[dst[e]], 1);
        csr_src[p] = src[e];
    }
}

// ---------------- gather-aggregate (mean fused) ----------------
__launch_bounds__(256)
__global__ void gather_kernel(const float* __restrict__ feat,
                              const int* __restrict__ off,
                              const int* __restrict__ deg_i,
                              const int* __restrict__ csr_src,
                              float* __restrict__ hneigh) {
    const int node = blockIdx.x * 2 + (threadIdx.x >> 7);
    const int k = threadIdx.x & (D - 1);
    if (node >= N_NODES) return;
    const int s0 = off[node];
    const int cnt = deg_i[node];
    float acc = 0.f;
    int e = s0;
    const int e4 = s0 + (cnt & ~3);
    for (; e < e4; e += 4) {
        const int a = csr_src[e];
        const int b = csr_src[e + 1];
        const int c = csr_src[e + 2];
        const int d = csr_src[e + 3];
        const float fa = feat[(size_t)a * D + k];
        const float fb = feat[(size_t)b * D + k];
        const float fc = feat[(size_t)c * D + k];
        const float fd = feat[(size_t)d * D + k];
        acc += fa; acc += fb; acc += fc; acc += fd;
    }
    for (; e < s0 + cnt; ++e)
        acc += feat[(size_t)csr_src[e] * D + k];
    const float sc = 1.f / fmaxf((float)cnt, 1.f);
    hneigh[(size_t)node * D + k] = acc * sc;
}

// ---------------- fused GEMM: out = feat@Wself^T + b + hneigh@Wneigh^T ----------------
__launch_bounds__(256)
__global__ void gemm_kernel(const float* __restrict__ feat,
                            const float* __restrict__ Wself,
                            const float* __restrict__ Wneigh,
                            const float* __restrict__ bias,
                            const float* __restrict__ hneigh,
                            float* __restrict__ out) {
    __shared__ __align__(16) float As[TM * ASTRIDE];
    __shared__ __align__(16) float Ws[D * ASTRIDE];

    const int tid = threadIdx.x;
    const int tx = tid & 15;   // output-feature group: j = tx + 16*r
    const int ty = tid >> 4;   // node group: n = row0 + ty*4 + i
    const int row0 = blockIdx.x * TM;

    float acc[4][8];
#pragma unroll
    for (int i = 0; i < 4; ++i)
#pragma unroll
        for (int r = 0; r < 8; ++r) acc[i][r] = 0.f;

#pragma unroll 1
    for (int phase = 0; phase < 2; ++phase) {
        const float* __restrict__ A = (phase == 0) ? feat : hneigh;
        const float* __restrict__ W = (phase == 0) ? Wself : Wneigh;
#pragma unroll 1
        for (int kb = 0; kb < D; kb += TKC) {
            __syncthreads();   // previous compute done before LDS overwrite
#pragma unroll
            for (int i = 0; i < 4; ++i) {
                const int elem = tid + i * 256;
                const int arow = elem >> 4;   // 0..63
                const int c4   = elem & 15;   // 0..15
                const int grow = row0 + arow;
                float4 v = make_float4(0.f, 0.f, 0.f, 0.f);
                if (grow < N_NODES)
                    v = *(const float4*)&A[(size_t)grow * D + kb + c4 * 4];
                *(float4*)&As[arow * ASTRIDE + c4 * 4] = v;
            }
#pragma unroll
            for (int i = 0; i < 8; ++i) {
                const int elem = tid + i * 256;
                const int wrow = elem >> 4;   // 0..127
                const int c4   = elem & 15;
                const float4 v = *(const float4*)&W[(size_t)wrow * D + kb + c4 * 4];
                *(float4*)&Ws[wrow * ASTRIDE + c4 * 4] = v;
            }
            __syncthreads();
#pragma unroll
            for (int k4 = 0; k4 < TKC / 4; ++k4) {
                float4 a[4];
#pragma unroll
                for (int i = 0; i < 4; ++i)
                    a[i] = *(const float4*)&As[(ty * 4 + i) * ASTRIDE + k4 * 4];
#pragma unroll
                for (int r = 0; r < 8; ++r) {
                    const float4 w = *(const float4*)&Ws[(tx + 16 * r) * ASTRIDE + k4 * 4];
#pragma unroll
                    for (int i = 0; i < 4; ++i)
                        acc[i][r] += a[i].x * w.x + a[i].y * w.y
                                   + a[i].z * w.z + a[i].w * w.w;
                }
            }
        }
    }

    float bv[8];
#pragma unroll
    for (int r = 0; r < 8; ++r) bv[r] = bias[tx + 16 * r];

#pragma unroll
    for (int i = 0; i < 4; ++i) {
        const int grow = row0 + ty * 4 + i;
        if (grow < N_NODES) {
#pragma unroll
            for (int r = 0; r < 8; ++r)
                out[(size_t)grow * D + tx + 16 * r] = acc[i][r] + bv[r];
        }
    }
}

extern "C" void kernel_launch(void* const* d_in, const int* in_sizes, int n_in,
                              void* d_out, int out_size, void* d_ws, size_t ws_size,
                              hipStream_t stream) {
    const float* feat  = (const float*)d_in[0];
    const float* Wn    = (const float*)d_in[1];  // W_neigh
    const float* Wsf   = (const float*)d_in[2];  // W_self
    const float* bself = (const float*)d_in[3];
    const int*   src   = (const int*)d_in[4];
    const int*   dst   = (const int*)d_in[5];
    float* out = (float*)d_out;

    // workspace layout
    float* hneigh    = (float*)d_ws;                           // N*D floats
    int*   deg_i     = (int*)(hneigh + (size_t)N_NODES * D);   // N ints
    int*   off       = deg_i + N_NODES;                        // N ints
    int*   cursor    = off + N_NODES;                          // N ints
    int*   blocksums = cursor + N_NODES;                       // NB_SCAN ints (pad 256)
    int*   csr_src   = blocksums + 256;                        // E ints

    const int eblocks = (N_EDGES + 255) / 256;

    zero_deg_kernel<<<NB_SCAN, 256, 0, stream>>>(deg_i);
    count_kernel<<<eblocks, 256, 0, stream>>>(dst, deg_i);
    scan_a_kernel<<<NB_SCAN, 256, 0, stream>>>(deg_i, blocksums);
    scan_b_kernel<<<1, 64, 0, stream>>>(blocksums);
    scan_c_kernel<<<NB_SCAN, 256, 0, stream>>>(deg_i, blocksums, off, cursor);
    scatter_kernel<<<eblocks, 256, 0, stream>>>(src, dst, cursor, csr_src);
    gather_kernel<<<(N_NODES + 1) / 2, 256, 0, stream>>>(feat, off, deg_i, csr_src, hneigh);
    gemm_kernel<<<(N_NODES + TM - 1) / TM, 256, 0, stream>>>(
        feat, Wsf, Wn, bself, hneigh, out);
}

// Round 3
// 200.566 us; speedup vs baseline: 2.8039x; 1.7325x over previous
//
#include <hip/hip_runtime.h>
#include <cstddef>
#include <cstdint>

#define N_NODES 50000
#define N_EDGES 800000
#define D 128
#define NB_SCAN ((N_NODES + 255) / 256)

typedef __attribute__((ext_vector_type(8))) short bf16x8;
typedef __attribute__((ext_vector_type(16))) float f32x16;

__device__ __forceinline__ unsigned short f32_to_bf16_rne(float x) {
    unsigned u = __builtin_bit_cast(unsigned, x);
    unsigned r = (u + 0x7FFFu + ((u >> 16) & 1u)) >> 16;
    return (unsigned short)r;
}
__device__ __forceinline__ float bf16_to_f32(unsigned short h) {
    unsigned u = ((unsigned)h) << 16;
    return __builtin_bit_cast(float, u);
}

// ---------------- zero degree counters ----------------
__global__ void zero_deg_kernel(int* __restrict__ deg_i) {
    int i = blockIdx.x * blockDim.x + threadIdx.x;
    if (i < N_NODES) deg_i[i] = 0;
}

// ---------------- per-dst degree count ----------------
__launch_bounds__(256)
__global__ void count_kernel(const int* __restrict__ dst, int* __restrict__ deg_i) {
    int e = blockIdx.x * blockDim.x + threadIdx.x;
    if (e < N_EDGES) atomicAdd(&deg_i[dst[e]], 1);
}

// ---------------- scan part a: per-block sums ----------------
__launch_bounds__(256)
__global__ void scan_a_kernel(const int* __restrict__ deg_i, int* __restrict__ blocksums) {
    __shared__ int s[256];
    const int t = threadIdx.x;
    const int i = blockIdx.x * 256 + t;
    s[t] = (i < N_NODES) ? deg_i[i] : 0;
    __syncthreads();
    for (int d = 128; d > 0; d >>= 1) {
        if (t < d) s[t] += s[t + d];
        __syncthreads();
    }
    if (t == 0) blocksums[blockIdx.x] = s[0];
}

// ---------------- scan part b: exclusive scan of block sums (1 block) ----------------
__global__ void scan_b_kernel(int* __restrict__ blocksums) {
    if (threadIdx.x == 0 && blockIdx.x == 0) {
        int run = 0;
        for (int b = 0; b < NB_SCAN; ++b) {
            int v = blocksums[b];
            blocksums[b] = run;
            run += v;
        }
    }
}

// ---------------- scan part c: per-block exclusive scan + base ----------------
__launch_bounds__(256)
__global__ void scan_c_kernel(const int* __restrict__ deg_i,
                              const int* __restrict__ blocksums,
                              int* __restrict__ off,
                              int* __restrict__ cursor) {
    __shared__ int s[256];
    const int t = threadIdx.x;
    const int i = blockIdx.x * 256 + t;
    const int c = (i < N_NODES) ? deg_i[i] : 0;
    s[t] = c;
    __syncthreads();
    for (int d = 1; d < 256; d <<= 1) {
        int v = 0;
        if (t >= d) v = s[t - d];
        __syncthreads();
        s[t] += v;
        __syncthreads();
    }
    if (i < N_NODES) {
        const int excl = s[t] - c + blocksums[blockIdx.x];
        off[i] = excl;
        cursor[i] = excl;
    }
}

// ---------------- scatter edges into CSR ----------------
__launch_bounds__(256)
__global__ void scatter_kernel(const int* __restrict__ src,
                               const int* __restrict__ dst,
                               int* __restrict__ cursor,
                               int* __restrict__ csr_src) {
    int e = blockIdx.x * blockDim.x + threadIdx.x;
    if (e < N_EDGES) {
        const int p = atomicAdd(&cursor[dst[e]], 1);
        csr_src[p] = src[e];
    }
}

// ---------------- gather-aggregate (mean fused) ----------------
__launch_bounds__(256)
__global__ void gather_kernel(const float* __restrict__ feat,
                              const int* __restrict__ off,
                              const int* __restrict__ deg_i,
                              const int* __restrict__ csr_src,
                              float* __restrict__ hneigh) {
    const int node = blockIdx.x * 2 + (threadIdx.x >> 7);
    const int k = threadIdx.x & (D - 1);
    if (node >= N_NODES) return;
    const int s0 = off[node];
    const int cnt = deg_i[node];
    float acc = 0.f;
    int e = s0;
    const int e4 = s0 + (cnt & ~3);
    for (; e < e4; e += 4) {
        const int a = csr_src[e];
        const int b = csr_src[e + 1];
        const int c = csr_src[e + 2];
        const int d = csr_src[e + 3];
        const float fa = feat[(size_t)a * D + k];
        const float fb = feat[(size_t)b * D + k];
        const float fc = feat[(size_t)c * D + k];
        const float fd = feat[(size_t)d * D + k];
        acc += fa; acc += fb; acc += fc; acc += fd;
    }
    for (; e < s0 + cnt; ++e)
        acc += feat[(size_t)csr_src[e] * D + k];
    const float sc = 1.f / fmaxf((float)cnt, 1.f);
    hneigh[(size_t)node * D + k] = acc * sc;
}

// ---------------- W pre-split into MFMA-fragment-linear layout ----------------
// Layout per (phase, kbi) image of 4096 bf16:
//   element (j, k) with k = kbi*32 + c*8 + e, c in 0..3:
//   p=j>>5, ks=c>>1, g=c&1  ->  idx = ((p*2+ks)*64 + (j&31) + 32*g)*8 + e
__global__ void wsplit_kernel(const float* __restrict__ Wself,
                              const float* __restrict__ Wneigh,
                              unsigned short* __restrict__ Wf_hi,
                              unsigned short* __restrict__ Wf_lo) {
    const int unit = blockIdx.x * 256 + threadIdx.x;
    if (unit >= 4096) return;
    const int phase = unit >> 11;        // 0..1
    const int kbi   = (unit >> 9) & 3;   // 0..3
    const int u     = unit & 511;
    const int j     = u & 127;
    const int c     = u >> 7;            // 0..3
    const float* __restrict__ W = phase ? Wneigh : Wself;
    const float* gp = &W[(size_t)j * D + kbi * 32 + c * 8];
    const int p = j >> 5, ks = c >> 1, g = c & 1;
    const size_t base = (size_t)(phase * 4 + kbi) * 4096
                      + (size_t)(((p * 2 + ks) * 64) + (j & 31) + 32 * g) * 8;
#pragma unroll
    for (int e = 0; e < 8; ++e) {
        const float x = gp[e];
        const unsigned short h = f32_to_bf16_rne(x);
        Wf_hi[base + e] = h;
        Wf_lo[base + e] = f32_to_bf16_rne(x - bf16_to_f32(h));
    }
}

// ---------------- MFMA GEMM, bf16x3 fp32 emulation ----------------
// out[n][j] = sum_k feat[n,k]*Wself[j,k] + sum_k hneigh[n,k]*Wneigh[j,k] + b[j]
// block: 128 rows x 128 cols, 4 waves (wave = 32 rows x 128 cols)
__launch_bounds__(256)
__global__ void gemm_kernel(const float* __restrict__ feat,
                            const float* __restrict__ hneigh,
                            const unsigned short* __restrict__ Wf_hi,
                            const unsigned short* __restrict__ Wf_lo,
                            const float* __restrict__ bias,
                            float* __restrict__ out) {
    __shared__ __align__(16) unsigned short sA_hi[4096];
    __shared__ __align__(16) unsigned short sA_lo[4096];
    __shared__ __align__(16) unsigned short sW_hi[4096];
    __shared__ __align__(16) unsigned short sW_lo[4096];

    const int tid  = threadIdx.x;
    const int wv   = tid >> 6;   // wave 0..3 -> A panel (rows wv*32..wv*32+31)
    const int l    = tid & 63;
    const int row0 = blockIdx.x * 128;

    f32x16 acc[4] = {};

#pragma unroll 1
    for (int blk = 0; blk < 8; ++blk) {
        const int kbi = blk & 3;
        const float* __restrict__ A = (blk < 4) ? feat : hneigh;

        __syncthreads();   // previous MFMA reads done before overwrite

        // ---- stage W (already frag-layout in global): contiguous copy ----
        {
            const size_t gbase = (size_t)blk * 4096;
#pragma unroll
            for (int i = 0; i < 2; ++i) {
                const int off = (i * 256 + tid) * 8;
                *(bf16x8*)&sW_hi[off] = *(const bf16x8*)&Wf_hi[gbase + off];
                *(bf16x8*)&sW_lo[off] = *(const bf16x8*)&Wf_lo[gbase + off];
            }
        }
        // ---- stage A: f32 load -> hi/lo bf16 split -> frag-linear LDS ----
#pragma unroll
        for (int i = 0; i < 2; ++i) {
            const int u   = i * 256 + tid;   // 0..511 = 128 rows x 4 chunks
            const int row = u & 127;
            const int c   = u >> 7;          // 8-k chunk within the 32-k block
            const int grow = row0 + row;
            float v[8];
            if (grow < N_NODES) {
                const float* gp = &A[(size_t)grow * D + kbi * 32 + c * 8];
                const float4 a = *(const float4*)gp;
                const float4 b = *(const float4*)(gp + 4);
                v[0] = a.x; v[1] = a.y; v[2] = a.z; v[3] = a.w;
                v[4] = b.x; v[5] = b.y; v[6] = b.z; v[7] = b.w;
            } else {
#pragma unroll
                for (int e = 0; e < 8; ++e) v[e] = 0.f;
            }
            bf16x8 hv, lv;
#pragma unroll
            for (int e = 0; e < 8; ++e) {
                const unsigned short h = f32_to_bf16_rne(v[e]);
                hv[e] = (short)h;
                lv[e] = (short)f32_to_bf16_rne(v[e] - bf16_to_f32(h));
            }
            const int p = row >> 5, ks = c >> 1, g = c & 1;
            const int off = ((p * 2 + ks) * 64 + (row & 31) + 32 * g) * 8;
            *(bf16x8*)&sA_hi[off] = hv;
            *(bf16x8*)&sA_lo[off] = lv;
        }
        __syncthreads();

        // ---- MFMA: 2 k-steps of 16, 12 MFMA each ----
#pragma unroll
        for (int ks = 0; ks < 2; ++ks) {
            const bf16x8 a_hi = *(const bf16x8*)&sA_hi[((wv * 2 + ks) * 64 + l) * 8];
            const bf16x8 a_lo = *(const bf16x8*)&sA_lo[((wv * 2 + ks) * 64 + l) * 8];
            bf16x8 w_hi[4], w_lo[4];
#pragma unroll
            for (int n = 0; n < 4; ++n) {
                w_hi[n] = *(const bf16x8*)&sW_hi[((n * 2 + ks) * 64 + l) * 8];
                w_lo[n] = *(const bf16x8*)&sW_lo[((n * 2 + ks) * 64 + l) * 8];
            }
#pragma unroll
            for (int n = 0; n < 4; ++n)
                acc[n] = __builtin_amdgcn_mfma_f32_32x32x16_bf16(a_hi, w_hi[n], acc[n], 0, 0, 0);
#pragma unroll
            for (int n = 0; n < 4; ++n)
                acc[n] = __builtin_amdgcn_mfma_f32_32x32x16_bf16(a_hi, w_lo[n], acc[n], 0, 0, 0);
#pragma unroll
            for (int n = 0; n < 4; ++n)
                acc[n] = __builtin_amdgcn_mfma_f32_32x32x16_bf16(a_lo, w_hi[n], acc[n], 0, 0, 0);
        }
    }

    // ---- epilogue: C/D layout col=l&31, row=(r&3)+8*(r>>2)+4*(l>>5) ----
    const int col = l & 31;
    const int hi2 = l >> 5;
    float bv[4];
#pragma unroll
    for (int n = 0; n < 4; ++n) bv[n] = bias[n * 32 + col];
#pragma unroll
    for (int r = 0; r < 16; ++r) {
        const int rloc = (r & 3) + 8 * (r >> 2) + 4 * hi2;
        const int grow = row0 + wv * 32 + rloc;
        if (grow < N_NODES) {
#pragma unroll
            for (int n = 0; n < 4; ++n)
                out[(size_t)grow * D + n * 32 + col] = acc[n][r] + bv[n];
        }
    }
}

extern "C" void kernel_launch(void* const* d_in, const int* in_sizes, int n_in,
                              void* d_out, int out_size, void* d_ws, size_t ws_size,
                              hipStream_t stream) {
    const float* feat  = (const float*)d_in[0];
    const float* Wn    = (const float*)d_in[1];  // W_neigh
    const float* Wsf   = (const float*)d_in[2];  // W_self
    const float* bself = (const float*)d_in[3];
    const int*   src   = (const int*)d_in[4];
    const int*   dst   = (const int*)d_in[5];
    float* out = (float*)d_out;

    // workspace layout (16B-aligned sections)
    float* hneigh    = (float*)d_ws;                           // N*D floats
    int*   deg_i     = (int*)(hneigh + (size_t)N_NODES * D);   // N ints
    int*   off       = deg_i + N_NODES;                        // N ints
    int*   cursor    = off + N_NODES;                          // N ints
    int*   blocksums = cursor + N_NODES;                       // 256 ints
    int*   csr_src   = blocksums + 256;                        // E ints
    unsigned short* Wf_hi = (unsigned short*)(csr_src + N_EDGES);  // 8*4096 bf16
    unsigned short* Wf_lo = Wf_hi + 8 * 4096;                      // 8*4096 bf16

    const int eblocks = (N_EDGES + 255) / 256;

    zero_deg_kernel<<<NB_SCAN, 256, 0, stream>>>(deg_i);
    count_kernel<<<eblocks, 256, 0, stream>>>(dst, deg_i);
    scan_a_kernel<<<NB_SCAN, 256, 0, stream>>>(deg_i, blocksums);
    scan_b_kernel<<<1, 64, 0, stream>>>(blocksums);
    scan_c_kernel<<<NB_SCAN, 256, 0, stream>>>(deg_i, blocksums, off, cursor);
    scatter_kernel<<<eblocks, 256, 0, stream>>>(src, dst, cursor, csr_src);
    wsplit_kernel<<<16, 256, 0, stream>>>(Wsf, Wn, Wf_hi, Wf_lo);
    gather_kernel<<<(N_NODES + 1) / 2, 256, 0, stream>>>(feat, off, deg_i, csr_src, hneigh);

    const int gblocks = (N_NODES + 127) / 128;   // 391
    gemm_kernel<<<gblocks, 256, 0, stream>>>(feat, hneigh, Wf_hi, Wf_lo, bself, out);
}

// Round 4
// 180.392 us; speedup vs baseline: 3.1175x; 1.1118x over previous
//
#include <hip/hip_runtime.h>
#include <cstddef>
#include <cstdint>

#define N_NODES 50000
#define N_EDGES 800000
#define D 128
#define NB_SCAN ((N_NODES + 255) / 256)

typedef __attribute__((ext_vector_type(8))) short bf16x8;
typedef __attribute__((ext_vector_type(16))) float f32x16;

__device__ __forceinline__ unsigned short f32_to_bf16_rne(float x) {
    unsigned u = __builtin_bit_cast(unsigned, x);
    unsigned r = (u + 0x7FFFu + ((u >> 16) & 1u)) >> 16;
    return (unsigned short)r;
}
__device__ __forceinline__ float bf16_to_f32(unsigned short h) {
    unsigned u = ((unsigned)h) << 16;
    return __builtin_bit_cast(float, u);
}
__device__ __forceinline__ float bf16lo_f32(unsigned u) {
    return __builtin_bit_cast(float, u << 16);
}
__device__ __forceinline__ float bf16hi_f32(unsigned u) {
    return __builtin_bit_cast(float, u & 0xFFFF0000u);
}

// ---------------- feat f32 -> bf16 row table ----------------
__launch_bounds__(256)
__global__ void fconv_kernel(const float* __restrict__ feat,
                             unsigned short* __restrict__ featb) {
    const int i = blockIdx.x * 256 + threadIdx.x;   // 8 floats per thread
    if (i >= N_NODES * D / 8) return;
    const float* gp = feat + (size_t)i * 8;
    const float4 a = *(const float4*)gp;
    const float4 b = *(const float4*)(gp + 4);
    bf16x8 h;
    h[0] = (short)f32_to_bf16_rne(a.x); h[1] = (short)f32_to_bf16_rne(a.y);
    h[2] = (short)f32_to_bf16_rne(a.z); h[3] = (short)f32_to_bf16_rne(a.w);
    h[4] = (short)f32_to_bf16_rne(b.x); h[5] = (short)f32_to_bf16_rne(b.y);
    h[6] = (short)f32_to_bf16_rne(b.z); h[7] = (short)f32_to_bf16_rne(b.w);
    *(bf16x8*)&featb[(size_t)i * 8] = h;
}

// ---------------- zero degree counters ----------------
__global__ void zero_deg_kernel(int* __restrict__ deg_i) {
    int i = blockIdx.x * blockDim.x + threadIdx.x;
    if (i < N_NODES) deg_i[i] = 0;
}

// ---------------- per-dst degree count ----------------
__launch_bounds__(256)
__global__ void count_kernel(const int* __restrict__ dst, int* __restrict__ deg_i) {
    int e = blockIdx.x * blockDim.x + threadIdx.x;
    if (e < N_EDGES) atomicAdd(&deg_i[dst[e]], 1);
}

// ---------------- scan part a: per-block sums ----------------
__launch_bounds__(256)
__global__ void scan_a_kernel(const int* __restrict__ deg_i, int* __restrict__ blocksums) {
    __shared__ int s[256];
    const int t = threadIdx.x;
    const int i = blockIdx.x * 256 + t;
    s[t] = (i < N_NODES) ? deg_i[i] : 0;
    __syncthreads();
    for (int d = 128; d > 0; d >>= 1) {
        if (t < d) s[t] += s[t + d];
        __syncthreads();
    }
    if (t == 0) blocksums[blockIdx.x] = s[0];
}

// ---------------- scan part b: exclusive scan of block sums (1 block) ----------------
__global__ void scan_b_kernel(int* __restrict__ blocksums) {
    if (threadIdx.x == 0 && blockIdx.x == 0) {
        int run = 0;
        for (int b = 0; b < NB_SCAN; ++b) {
            int v = blocksums[b];
            blocksums[b] = run;
            run += v;
        }
    }
}

// ---------------- scan part c: per-block exclusive scan + base ----------------
__launch_bounds__(256)
__global__ void scan_c_kernel(const int* __restrict__ deg_i,
                              const int* __restrict__ blocksums,
                              int* __restrict__ off,
                              int* __restrict__ cursor) {
    __shared__ int s[256];
    const int t = threadIdx.x;
    const int i = blockIdx.x * 256 + t;
    const int c = (i < N_NODES) ? deg_i[i] : 0;
    s[t] = c;
    __syncthreads();
    for (int d = 1; d < 256; d <<= 1) {
        int v = 0;
        if (t >= d) v = s[t - d];
        __syncthreads();
        s[t] += v;
        __syncthreads();
    }
    if (i < N_NODES) {
        const int excl = s[t] - c + blocksums[blockIdx.x];
        off[i] = excl;
        cursor[i] = excl;
    }
}

// ---------------- scatter edges into CSR ----------------
__launch_bounds__(256)
__global__ void scatter_kernel(const int* __restrict__ src,
                               const int* __restrict__ dst,
                               int* __restrict__ cursor,
                               int* __restrict__ csr_src) {
    int e = blockIdx.x * blockDim.x + threadIdx.x;
    if (e < N_EDGES) {
        const int p = atomicAdd(&cursor[dst[e]], 1);
        csr_src[p] = src[e];
    }
}

// ---------------- gather-aggregate (bf16 rows, mean fused) ----------------
// one wave per node; lane handles features {2*lane, 2*lane+1}
__launch_bounds__(256)
__global__ void gather_kernel(const unsigned short* __restrict__ featb,
                              const int* __restrict__ off,
                              const int* __restrict__ deg_i,
                              const int* __restrict__ csr_src,
                              float* __restrict__ hneigh) {
    const int node = blockIdx.x * 4 + (threadIdx.x >> 6);
    const int lane = threadIdx.x & 63;
    if (node >= N_NODES) return;
    const int s0 = off[node];
    const int cnt = deg_i[node];
    float a0 = 0.f, a1 = 0.f;
    int e = s0;
    const int e4 = s0 + (cnt & ~3);
    for (; e < e4; e += 4) {
        const int i0 = csr_src[e];
        const int i1 = csr_src[e + 1];
        const int i2 = csr_src[e + 2];
        const int i3 = csr_src[e + 3];
        const unsigned u0 = *(const unsigned*)&featb[(size_t)i0 * D + lane * 2];
        const unsigned u1 = *(const unsigned*)&featb[(size_t)i1 * D + lane * 2];
        const unsigned u2 = *(const unsigned*)&featb[(size_t)i2 * D + lane * 2];
        const unsigned u3 = *(const unsigned*)&featb[(size_t)i3 * D + lane * 2];
        a0 += bf16lo_f32(u0); a1 += bf16hi_f32(u0);
        a0 += bf16lo_f32(u1); a1 += bf16hi_f32(u1);
        a0 += bf16lo_f32(u2); a1 += bf16hi_f32(u2);
        a0 += bf16lo_f32(u3); a1 += bf16hi_f32(u3);
    }
    for (; e < s0 + cnt; ++e) {
        const unsigned u = *(const unsigned*)&featb[(size_t)csr_src[e] * D + lane * 2];
        a0 += bf16lo_f32(u); a1 += bf16hi_f32(u);
    }
    const float sc = 1.f / fmaxf((float)cnt, 1.f);
    *(float2*)&hneigh[(size_t)node * D + lane * 2] = make_float2(a0 * sc, a1 * sc);
}

// ---------------- W pre-split into MFMA-fragment-linear layout ----------------
__global__ void wsplit_kernel(const float* __restrict__ Wself,
                              const float* __restrict__ Wneigh,
                              unsigned short* __restrict__ Wf_hi,
                              unsigned short* __restrict__ Wf_lo) {
    const int unit = blockIdx.x * 256 + threadIdx.x;
    if (unit >= 4096) return;
    const int phase = unit >> 11;        // 0..1
    const int kbi   = (unit >> 9) & 3;   // 0..3
    const int u     = unit & 511;
    const int j     = u & 127;
    const int c     = u >> 7;            // 0..3
    const float* __restrict__ W = phase ? Wneigh : Wself;
    const float* gp = &W[(size_t)j * D + kbi * 32 + c * 8];
    const int p = j >> 5, ks = c >> 1, g = c & 1;
    const size_t base = (size_t)(phase * 4 + kbi) * 4096
                      + (size_t)(((p * 2 + ks) * 64) + (j & 31) + 32 * g) * 8;
#pragma unroll
    for (int e = 0; e < 8; ++e) {
        const float x = gp[e];
        const unsigned short h = f32_to_bf16_rne(x);
        Wf_hi[base + e] = h;
        Wf_lo[base + e] = f32_to_bf16_rne(x - bf16_to_f32(h));
    }
}

// ---------------- MFMA GEMM, bf16x3 fp32 emulation ----------------
__launch_bounds__(256)
__global__ void gemm_kernel(const float* __restrict__ feat,
                            const float* __restrict__ hneigh,
                            const unsigned short* __restrict__ Wf_hi,
                            const unsigned short* __restrict__ Wf_lo,
                            const float* __restrict__ bias,
                            float* __restrict__ out) {
    __shared__ __align__(16) unsigned short sA_hi[4096];
    __shared__ __align__(16) unsigned short sA_lo[4096];
    __shared__ __align__(16) unsigned short sW_hi[4096];
    __shared__ __align__(16) unsigned short sW_lo[4096];

    const int tid  = threadIdx.x;
    const int wv   = tid >> 6;   // wave 0..3 -> A panel (rows wv*32..wv*32+31)
    const int l    = tid & 63;
    const int row0 = blockIdx.x * 128;

    f32x16 acc[4] = {};

#pragma unroll 1
    for (int blk = 0; blk < 8; ++blk) {
        const int kbi = blk & 3;
        const float* __restrict__ A = (blk < 4) ? feat : hneigh;

        __syncthreads();   // previous MFMA reads done before overwrite

        // ---- stage W (already frag-layout in global): contiguous copy ----
        {
            const size_t gbase = (size_t)blk * 4096;
#pragma unroll
            for (int i = 0; i < 2; ++i) {
                const int off = (i * 256 + tid) * 8;
                *(bf16x8*)&sW_hi[off] = *(const bf16x8*)&Wf_hi[gbase + off];
                *(bf16x8*)&sW_lo[off] = *(const bf16x8*)&Wf_lo[gbase + off];
            }
        }
        // ---- stage A: f32 load -> hi/lo bf16 split -> frag-linear LDS ----
#pragma unroll
        for (int i = 0; i < 2; ++i) {
            const int u   = i * 256 + tid;   // 0..511 = 128 rows x 4 chunks
            const int row = u & 127;
            const int c   = u >> 7;          // 8-k chunk within the 32-k block
            const int grow = row0 + row;
            float v[8];
            if (grow < N_NODES) {
                const float* gp = &A[(size_t)grow * D + kbi * 32 + c * 8];
                const float4 a = *(const float4*)gp;
                const float4 b = *(const float4*)(gp + 4);
                v[0] = a.x; v[1] = a.y; v[2] = a.z; v[3] = a.w;
                v[4] = b.x; v[5] = b.y; v[6] = b.z; v[7] = b.w;
            } else {
#pragma unroll
                for (int e = 0; e < 8; ++e) v[e] = 0.f;
            }
            bf16x8 hv, lv;
#pragma unroll
            for (int e = 0; e < 8; ++e) {
                const unsigned short h = f32_to_bf16_rne(v[e]);
                hv[e] = (short)h;
                lv[e] = (short)f32_to_bf16_rne(v[e] - bf16_to_f32(h));
            }
            const int p = row >> 5, ks = c >> 1, g = c & 1;
            const int off = ((p * 2 + ks) * 64 + (row & 31) + 32 * g) * 8;
            *(bf16x8*)&sA_hi[off] = hv;
            *(bf16x8*)&sA_lo[off] = lv;
        }
        __syncthreads();

        // ---- MFMA: 2 k-steps of 16, 12 MFMA each ----
#pragma unroll
        for (int ks = 0; ks < 2; ++ks) {
            const bf16x8 a_hi = *(const bf16x8*)&sA_hi[((wv * 2 + ks) * 64 + l) * 8];
            const bf16x8 a_lo = *(const bf16x8*)&sA_lo[((wv * 2 + ks) * 64 + l) * 8];
            bf16x8 w_hi[4], w_lo[4];
#pragma unroll
            for (int n = 0; n < 4; ++n) {
                w_hi[n] = *(const bf16x8*)&sW_hi[((n * 2 + ks) * 64 + l) * 8];
                w_lo[n] = *(const bf16x8*)&sW_lo[((n * 2 + ks) * 64 + l) * 8];
            }
#pragma unroll
            for (int n = 0; n < 4; ++n)
                acc[n] = __builtin_amdgcn_mfma_f32_32x32x16_bf16(a_hi, w_hi[n], acc[n], 0, 0, 0);
#pragma unroll
            for (int n = 0; n < 4; ++n)
                acc[n] = __builtin_amdgcn_mfma_f32_32x32x16_bf16(a_hi, w_lo[n], acc[n], 0, 0, 0);
#pragma unroll
            for (int n = 0; n < 4; ++n)
                acc[n] = __builtin_amdgcn_mfma_f32_32x32x16_bf16(a_lo, w_hi[n], acc[n], 0, 0, 0);
        }
    }

    // ---- epilogue: C/D layout col=l&31, row=(r&3)+8*(r>>2)+4*(l>>5) ----
    const int col = l & 31;
    const int hi2 = l >> 5;
    float bv[4];
#pragma unroll
    for (int n = 0; n < 4; ++n) bv[n] = bias[n * 32 + col];
#pragma unroll
    for (int r = 0; r < 16; ++r) {
        const int rloc = (r & 3) + 8 * (r >> 2) + 4 * hi2;
        const int grow = row0 + wv * 32 + rloc;
        if (grow < N_NODES) {
#pragma unroll
            for (int n = 0; n < 4; ++n)
                out[(size_t)grow * D + n * 32 + col] = acc[n][r] + bv[n];
        }
    }
}

extern "C" void kernel_launch(void* const* d_in, const int* in_sizes, int n_in,
                              void* d_out, int out_size, void* d_ws, size_t ws_size,
                              hipStream_t stream) {
    const float* feat  = (const float*)d_in[0];
    const float* Wn    = (const float*)d_in[1];  // W_neigh
    const float* Wsf   = (const float*)d_in[2];  // W_self
    const float* bself = (const float*)d_in[3];
    const int*   src   = (const int*)d_in[4];
    const int*   dst   = (const int*)d_in[5];
    float* out = (float*)d_out;

    // workspace layout (16B-aligned sections)
    float* hneigh    = (float*)d_ws;                           // N*D floats
    int*   deg_i     = (int*)(hneigh + (size_t)N_NODES * D);   // N ints
    int*   off       = deg_i + N_NODES;                        // N ints
    int*   cursor    = off + N_NODES;                          // N ints
    int*   blocksums = cursor + N_NODES;                       // 256 ints
    int*   csr_src   = blocksums + 256;                        // E ints
    unsigned short* Wf_hi = (unsigned short*)(csr_src + N_EDGES);  // 8*4096 bf16
    unsigned short* Wf_lo = Wf_hi + 8 * 4096;                      // 8*4096 bf16
    unsigned short* featb = Wf_lo + 8 * 4096;                      // N*D bf16

    const int eblocks = (N_EDGES + 255) / 256;

    fconv_kernel<<<(N_NODES * D / 8 + 255) / 256, 256, 0, stream>>>(feat, featb);
    zero_deg_kernel<<<NB_SCAN, 256, 0, stream>>>(deg_i);
    count_kernel<<<eblocks, 256, 0, stream>>>(dst, deg_i);
    scan_a_kernel<<<NB_SCAN, 256, 0, stream>>>(deg_i, blocksums);
    scan_b_kernel<<<1, 64, 0, stream>>>(blocksums);
    scan_c_kernel<<<NB_SCAN, 256, 0, stream>>>(deg_i, blocksums, off, cursor);
    scatter_kernel<<<eblocks, 256, 0, stream>>>(src, dst, cursor, csr_src);
    wsplit_kernel<<<16, 256, 0, stream>>>(Wsf, Wn, Wf_hi, Wf_lo);
    gather_kernel<<<(N_NODES + 3) / 4, 256, 0, stream>>>(featb, off, deg_i, csr_src, hneigh);

    const int gblocks = (N_NODES + 127) / 128;   // 391
    gemm_kernel<<<gblocks, 256, 0, stream>>>(feat, hneigh, Wf_hi, Wf_lo, bself, out);
}

// Round 5
// 127.657 us; speedup vs baseline: 4.4054x; 1.4131x over previous
//
#include <hip/hip_runtime.h>
#include <cstddef>
#include <cstdint>

#define N_NODES 50000
#define N_EDGES 800000
#define D 128
#define NB_SCAN ((N_NODES + 255) / 256)   // 196
#define NWG 128                            // binning workgroups
#define EPW (N_EDGES / NWG)                // 6250 edges per wg
#define NBUCK 196                          // ceil(50000/256)

typedef __attribute__((ext_vector_type(8))) short bf16x8;
typedef __attribute__((ext_vector_type(16))) float f32x16;

__device__ __forceinline__ unsigned short f32_to_bf16_rne(float x) {
    unsigned u = __builtin_bit_cast(unsigned, x);
    unsigned r = (u + 0x7FFFu + ((u >> 16) & 1u)) >> 16;
    return (unsigned short)r;
}
__device__ __forceinline__ float bf16_to_f32(unsigned short h) {
    unsigned u = ((unsigned)h) << 16;
    return __builtin_bit_cast(float, u);
}
__device__ __forceinline__ float bf16lo_f32(unsigned u) {
    return __builtin_bit_cast(float, u << 16);
}
__device__ __forceinline__ float bf16hi_f32(unsigned u) {
    return __builtin_bit_cast(float, u & 0xFFFF0000u);
}

// ---------------- feat f32 -> bf16 row table ----------------
__launch_bounds__(256)
__global__ void fconv_kernel(const float* __restrict__ feat,
                             unsigned short* __restrict__ featb) {
    const int i = blockIdx.x * 256 + threadIdx.x;   // 8 floats per thread
    if (i >= N_NODES * D / 8) return;
    const float* gp = feat + (size_t)i * 8;
    const float4 a = *(const float4*)gp;
    const float4 b = *(const float4*)(gp + 4);
    bf16x8 h;
    h[0] = (short)f32_to_bf16_rne(a.x); h[1] = (short)f32_to_bf16_rne(a.y);
    h[2] = (short)f32_to_bf16_rne(a.z); h[3] = (short)f32_to_bf16_rne(a.w);
    h[4] = (short)f32_to_bf16_rne(b.x); h[5] = (short)f32_to_bf16_rne(b.y);
    h[6] = (short)f32_to_bf16_rne(b.z); h[7] = (short)f32_to_bf16_rne(b.w);
    *(bf16x8*)&featb[(size_t)i * 8] = h;
}

// ---------------- S1: per-wg bucket histogram ----------------
__launch_bounds__(256)
__global__ void s1_hist_kernel(const int* __restrict__ dst, int* __restrict__ ghist) {
    __shared__ int hist[256];
    const int t = threadIdx.x;
    const int w = blockIdx.x;
    hist[t] = 0;
    __syncthreads();
    const int base = w * EPW;
    for (int i = t; i < EPW; i += 256)
        atomicAdd(&hist[dst[base + i] >> 8], 1);
    __syncthreads();
    ghist[w * 256 + t] = hist[t];
}

// ---------------- S2: bucket scan -> gboff, per-(wg,bucket) cursors gpos ----------------
__launch_bounds__(256)
__global__ void s2_scan_kernel(const int* __restrict__ ghist,
                               int* __restrict__ gpos,
                               int* __restrict__ gboff) {
    __shared__ int s[256];
    const int b = threadIdx.x;
    int tot = 0;
    for (int w = 0; w < NWG; ++w) tot += ghist[w * 256 + b];
    s[b] = tot;
    __syncthreads();
    // inclusive Hillis-Steele scan
    for (int d = 1; d < 256; d <<= 1) {
        int v = 0;
        if (b >= d) v = s[b - d];
        __syncthreads();
        s[b] += v;
        __syncthreads();
    }
    const int boff = s[b] - tot;   // exclusive
    gboff[b] = boff;
    if (b == 255) gboff[256] = s[255];
    int run = boff;
    for (int w = 0; w < NWG; ++w) {
        gpos[w * 256 + b] = run;
        run += ghist[w * 256 + b];
    }
}

// ---------------- S3: bin edges into bucket-major (src,dst) pairs ----------------
__launch_bounds__(256)
__global__ void s3_bin_kernel(const int* __restrict__ src,
                              const int* __restrict__ dst,
                              const int* __restrict__ gpos,
                              uint2* __restrict__ binned) {
    __shared__ int cur[256];
    const int t = threadIdx.x;
    const int w = blockIdx.x;
    cur[t] = gpos[w * 256 + t];
    __syncthreads();
    const int base = w * EPW;
    for (int i = t; i < EPW; i += 256) {
        const int s = src[base + i];
        const int d = dst[base + i];
        const int p = atomicAdd(&cur[d >> 8], 1);
        binned[p] = make_uint2((unsigned)s, (unsigned)d);
    }
}

// ---------------- K_deg: per-node degree from binned pairs ----------------
__launch_bounds__(256)
__global__ void kdeg_kernel(const uint2* __restrict__ binned,
                            const int* __restrict__ gboff,
                            int* __restrict__ deg_i) {
    __shared__ int cnt[256];
    const int t = threadIdx.x;
    const int b = blockIdx.x;
    cnt[t] = 0;
    __syncthreads();
    const int lo = gboff[b], hi = gboff[b + 1];
    for (int i = lo + t; i < hi; i += 256)
        atomicAdd(&cnt[binned[i].y & 255u], 1);
    __syncthreads();
    const int node = b * 256 + t;
    if (node < N_NODES) deg_i[node] = cnt[t];
}

// ---------------- scan part a: per-block sums ----------------
__launch_bounds__(256)
__global__ void scan_a_kernel(const int* __restrict__ deg_i, int* __restrict__ blocksums) {
    __shared__ int s[256];
    const int t = threadIdx.x;
    const int i = blockIdx.x * 256 + t;
    s[t] = (i < N_NODES) ? deg_i[i] : 0;
    __syncthreads();
    for (int d = 128; d > 0; d >>= 1) {
        if (t < d) s[t] += s[t + d];
        __syncthreads();
    }
    if (t == 0) blocksums[blockIdx.x] = s[0];
}

// ---------------- scan part b ----------------
__global__ void scan_b_kernel(int* __restrict__ blocksums) {
    if (threadIdx.x == 0 && blockIdx.x == 0) {
        int run = 0;
        for (int b = 0; b < NB_SCAN; ++b) {
            int v = blocksums[b];
            blocksums[b] = run;
            run += v;
        }
    }
}

// ---------------- scan part c ----------------
__launch_bounds__(256)
__global__ void scan_c_kernel(const int* __restrict__ deg_i,
                              const int* __restrict__ blocksums,
                              int* __restrict__ off) {
    __shared__ int s[256];
    const int t = threadIdx.x;
    const int i = blockIdx.x * 256 + t;
    const int c = (i < N_NODES) ? deg_i[i] : 0;
    s[t] = c;
    __syncthreads();
    for (int d = 1; d < 256; d <<= 1) {
        int v = 0;
        if (t >= d) v = s[t - d];
        __syncthreads();
        s[t] += v;
        __syncthreads();
    }
    if (i < N_NODES) off[i] = s[t] - c + blocksums[blockIdx.x];
}

// ---------------- S4: final scatter within bucket (single-owner lines) ----------------
__launch_bounds__(256)
__global__ void s4_scatter_kernel(const uint2* __restrict__ binned,
                                  const int* __restrict__ gboff,
                                  const int* __restrict__ off,
                                  int* __restrict__ csr_src) {
    __shared__ int cur[256];
    const int t = threadIdx.x;
    const int b = blockIdx.x;
    const int node = b * 256 + t;
    cur[t] = (node < N_NODES) ? off[node] : 0;
    __syncthreads();
    const int lo = gboff[b], hi = gboff[b + 1];
    for (int i = lo + t; i < hi; i += 256) {
        const uint2 u = binned[i];
        const int p = atomicAdd(&cur[u.y & 255u], 1);
        csr_src[p] = (int)u.x;
    }
}

// ---------------- gather-aggregate (bf16 rows, mean fused) ----------------
__launch_bounds__(256)
__global__ void gather_kernel(const unsigned short* __restrict__ featb,
                              const int* __restrict__ off,
                              const int* __restrict__ deg_i,
                              const int* __restrict__ csr_src,
                              float* __restrict__ hneigh) {
    const int node = blockIdx.x * 4 + (threadIdx.x >> 6);
    const int lane = threadIdx.x & 63;
    if (node >= N_NODES) return;
    const int s0 = off[node];
    const int cnt = deg_i[node];
    float a0 = 0.f, a1 = 0.f;
    int e = s0;
    const int e4 = s0 + (cnt & ~3);
    for (; e < e4; e += 4) {
        const int i0 = csr_src[e];
        const int i1 = csr_src[e + 1];
        const int i2 = csr_src[e + 2];
        const int i3 = csr_src[e + 3];
        const unsigned u0 = *(const unsigned*)&featb[(size_t)i0 * D + lane * 2];
        const unsigned u1 = *(const unsigned*)&featb[(size_t)i1 * D + lane * 2];
        const unsigned u2 = *(const unsigned*)&featb[(size_t)i2 * D + lane * 2];
        const unsigned u3 = *(const unsigned*)&featb[(size_t)i3 * D + lane * 2];
        a0 += bf16lo_f32(u0); a1 += bf16hi_f32(u0);
        a0 += bf16lo_f32(u1); a1 += bf16hi_f32(u1);
        a0 += bf16lo_f32(u2); a1 += bf16hi_f32(u2);
        a0 += bf16lo_f32(u3); a1 += bf16hi_f32(u3);
    }
    for (; e < s0 + cnt; ++e) {
        const unsigned u = *(const unsigned*)&featb[(size_t)csr_src[e] * D + lane * 2];
        a0 += bf16lo_f32(u); a1 += bf16hi_f32(u);
    }
    const float sc = 1.f / fmaxf((float)cnt, 1.f);
    *(float2*)&hneigh[(size_t)node * D + lane * 2] = make_float2(a0 * sc, a1 * sc);
}

// ---------------- W pre-split into MFMA-fragment-linear layout ----------------
__global__ void wsplit_kernel(const float* __restrict__ Wself,
                              const float* __restrict__ Wneigh,
                              unsigned short* __restrict__ Wf_hi,
                              unsigned short* __restrict__ Wf_lo) {
    const int unit = blockIdx.x * 256 + threadIdx.x;
    if (unit >= 4096) return;
    const int phase = unit >> 11;        // 0..1
    const int kbi   = (unit >> 9) & 3;   // 0..3
    const int u     = unit & 511;
    const int j     = u & 127;
    const int c     = u >> 7;            // 0..3
    const float* __restrict__ W = phase ? Wneigh : Wself;
    const float* gp = &W[(size_t)j * D + kbi * 32 + c * 8];
    const int p = j >> 5, ks = c >> 1, g = c & 1;
    const size_t base = (size_t)(phase * 4 + kbi) * 4096
                      + (size_t)(((p * 2 + ks) * 64) + (j & 31) + 32 * g) * 8;
#pragma unroll
    for (int e = 0; e < 8; ++e) {
        const float x = gp[e];
        const unsigned short h = f32_to_bf16_rne(x);
        Wf_hi[base + e] = h;
        Wf_lo[base + e] = f32_to_bf16_rne(x - bf16_to_f32(h));
    }
}

// ---------------- MFMA GEMM, bf16x3 fp32 emulation ----------------
__launch_bounds__(256)
__global__ void gemm_kernel(const float* __restrict__ feat,
                            const float* __restrict__ hneigh,
                            const unsigned short* __restrict__ Wf_hi,
                            const unsigned short* __restrict__ Wf_lo,
                            const float* __restrict__ bias,
                            float* __restrict__ out) {
    __shared__ __align__(16) unsigned short sA_hi[4096];
    __shared__ __align__(16) unsigned short sA_lo[4096];
    __shared__ __align__(16) unsigned short sW_hi[4096];
    __shared__ __align__(16) unsigned short sW_lo[4096];

    const int tid  = threadIdx.x;
    const int wv   = tid >> 6;   // wave 0..3 -> A panel (rows wv*32..wv*32+31)
    const int l    = tid & 63;
    const int row0 = blockIdx.x * 128;

    f32x16 acc[4] = {};

#pragma unroll 1
    for (int blk = 0; blk < 8; ++blk) {
        const int kbi = blk & 3;
        const float* __restrict__ A = (blk < 4) ? feat : hneigh;

        __syncthreads();   // previous MFMA reads done before overwrite

        // ---- stage W (already frag-layout in global): contiguous copy ----
        {
            const size_t gbase = (size_t)blk * 4096;
#pragma unroll
            for (int i = 0; i < 2; ++i) {
                const int off = (i * 256 + tid) * 8;
                *(bf16x8*)&sW_hi[off] = *(const bf16x8*)&Wf_hi[gbase + off];
                *(bf16x8*)&sW_lo[off] = *(const bf16x8*)&Wf_lo[gbase + off];
            }
        }
        // ---- stage A: f32 load -> hi/lo bf16 split -> frag-linear LDS ----
#pragma unroll
        for (int i = 0; i < 2; ++i) {
            const int u   = i * 256 + tid;   // 0..511 = 128 rows x 4 chunks
            const int row = u & 127;
            const int c   = u >> 7;          // 8-k chunk within the 32-k block
            const int grow = row0 + row;
            float v[8];
            if (grow < N_NODES) {
                const float* gp = &A[(size_t)grow * D + kbi * 32 + c * 8];
                const float4 a = *(const float4*)gp;
                const float4 b = *(const float4*)(gp + 4);
                v[0] = a.x; v[1] = a.y; v[2] = a.z; v[3] = a.w;
                v[4] = b.x; v[5] = b.y; v[6] = b.z; v[7] = b.w;
            } else {
#pragma unroll
                for (int e = 0; e < 8; ++e) v[e] = 0.f;
            }
            bf16x8 hv, lv;
#pragma unroll
            for (int e = 0; e < 8; ++e) {
                const unsigned short h = f32_to_bf16_rne(v[e]);
                hv[e] = (short)h;
                lv[e] = (short)f32_to_bf16_rne(v[e] - bf16_to_f32(h));
            }
            const int p = row >> 5, ks = c >> 1, g = c & 1;
            const int off = ((p * 2 + ks) * 64 + (row & 31) + 32 * g) * 8;
            *(bf16x8*)&sA_hi[off] = hv;
            *(bf16x8*)&sA_lo[off] = lv;
        }
        __syncthreads();

        // ---- MFMA: 2 k-steps of 16, 12 MFMA each ----
#pragma unroll
        for (int ks = 0; ks < 2; ++ks) {
            const bf16x8 a_hi = *(const bf16x8*)&sA_hi[((wv * 2 + ks) * 64 + l) * 8];
            const bf16x8 a_lo = *(const bf16x8*)&sA_lo[((wv * 2 + ks) * 64 + l) * 8];
            bf16x8 w_hi[4], w_lo[4];
#pragma unroll
            for (int n = 0; n < 4; ++n) {
                w_hi[n] = *(const bf16x8*)&sW_hi[((n * 2 + ks) * 64 + l) * 8];
                w_lo[n] = *(const bf16x8*)&sW_lo[((n * 2 + ks) * 64 + l) * 8];
            }
#pragma unroll
            for (int n = 0; n < 4; ++n)
                acc[n] = __builtin_amdgcn_mfma_f32_32x32x16_bf16(a_hi, w_hi[n], acc[n], 0, 0, 0);
#pragma unroll
            for (int n = 0; n < 4; ++n)
                acc[n] = __builtin_amdgcn_mfma_f32_32x32x16_bf16(a_hi, w_lo[n], acc[n], 0, 0, 0);
#pragma unroll
            for (int n = 0; n < 4; ++n)
                acc[n] = __builtin_amdgcn_mfma_f32_32x32x16_bf16(a_lo, w_hi[n], acc[n], 0, 0, 0);
        }
    }

    // ---- epilogue: C/D layout col=l&31, row=(r&3)+8*(r>>2)+4*(l>>5) ----
    const int col = l & 31;
    const int hi2 = l >> 5;
    float bv[4];
#pragma unroll
    for (int n = 0; n < 4; ++n) bv[n] = bias[n * 32 + col];
#pragma unroll
    for (int r = 0; r < 16; ++r) {
        const int rloc = (r & 3) + 8 * (r >> 2) + 4 * hi2;
        const int grow = row0 + wv * 32 + rloc;
        if (grow < N_NODES) {
#pragma unroll
            for (int n = 0; n < 4; ++n)
                out[(size_t)grow * D + n * 32 + col] = acc[n][r] + bv[n];
        }
    }
}

extern "C" void kernel_launch(void* const* d_in, const int* in_sizes, int n_in,
                              void* d_out, int out_size, void* d_ws, size_t ws_size,
                              hipStream_t stream) {
    const float* feat  = (const float*)d_in[0];
    const float* Wn    = (const float*)d_in[1];  // W_neigh
    const float* Wsf   = (const float*)d_in[2];  // W_self
    const float* bself = (const float*)d_in[3];
    const int*   src   = (const int*)d_in[4];
    const int*   dst   = (const int*)d_in[5];
    float* out = (float*)d_out;

    // workspace layout (16B-aligned at front; binned right after hneigh keeps 8B align)
    float* hneigh    = (float*)d_ws;                           // N*D floats
    uint2* binned    = (uint2*)(hneigh + (size_t)N_NODES * D); // E uint2 (6.4MB)
    int*   deg_i     = (int*)(binned + N_EDGES);               // N ints
    int*   off       = deg_i + N_NODES;                        // N ints
    int*   blocksums = off + N_NODES;                          // 256 ints
    int*   csr_src   = blocksums + 256;                        // E ints
    int*   ghist     = csr_src + N_EDGES;                      // NWG*256 ints
    int*   gpos      = ghist + NWG * 256;                      // NWG*256 ints
    int*   gboff     = gpos + NWG * 256;                       // 260 ints
    unsigned short* Wf_hi = (unsigned short*)(gboff + 260);    // 8*4096 bf16
    unsigned short* Wf_lo = Wf_hi + 8 * 4096;                  // 8*4096 bf16
    unsigned short* featb = Wf_lo + 8 * 4096;                  // N*D bf16

    fconv_kernel<<<(N_NODES * D / 8 + 255) / 256, 256, 0, stream>>>(feat, featb);
    s1_hist_kernel<<<NWG, 256, 0, stream>>>(dst, ghist);
    s2_scan_kernel<<<1, 256, 0, stream>>>(ghist, gpos, gboff);
    s3_bin_kernel<<<NWG, 256, 0, stream>>>(src, dst, gpos, binned);
    kdeg_kernel<<<NBUCK, 256, 0, stream>>>(binned, gboff, deg_i);
    scan_a_kernel<<<NB_SCAN, 256, 0, stream>>>(deg_i, blocksums);
    scan_b_kernel<<<1, 64, 0, stream>>>(blocksums);
    scan_c_kernel<<<NB_SCAN, 256, 0, stream>>>(deg_i, blocksums, off);
    s4_scatter_kernel<<<NBUCK, 256, 0, stream>>>(binned, gboff, off, csr_src);
    wsplit_kernel<<<16, 256, 0, stream>>>(Wsf, Wn, Wf_hi, Wf_lo);
    gather_kernel<<<(N_NODES + 3) / 4, 256, 0, stream>>>(featb, off, deg_i, csr_src, hneigh);

    const int gblocks = (N_NODES + 127) / 128;   // 391
    gemm_kernel<<<gblocks, 256, 0, stream>>>(feat, hneigh, Wf_hi, Wf_lo, bself, out);
}

// Round 6
// 99.002 us; speedup vs baseline: 5.6805x; 1.2894x over previous
//
#include <hip/hip_runtime.h>
#include <cstddef>
#include <cstdint>

#define N_NODES 50000
#define N_EDGES 800000
#define D 128
#define NWG 128                            // binning workgroups
#define EPW (N_EDGES / NWG)                // 6250 edges per wg
#define NBUCK 196                          // ceil(50000/256)

typedef __attribute__((ext_vector_type(8))) short bf16x8;
typedef __attribute__((ext_vector_type(16))) float f32x16;

__device__ __forceinline__ unsigned short f32_to_bf16_rne(float x) {
    unsigned u = __builtin_bit_cast(unsigned, x);
    unsigned r = (u + 0x7FFFu + ((u >> 16) & 1u)) >> 16;
    return (unsigned short)r;
}
__device__ __forceinline__ float bf16lo_f32(unsigned u) {
    return __builtin_bit_cast(float, u << 16);
}
__device__ __forceinline__ float bf16hi_f32(unsigned u) {
    return __builtin_bit_cast(float, u & 0xFFFF0000u);
}

// ---------------- feat f32 -> bf16 row table ----------------
__launch_bounds__(256)
__global__ void fconv_kernel(const float* __restrict__ feat,
                             unsigned short* __restrict__ featb) {
    const int i = blockIdx.x * 256 + threadIdx.x;   // 8 floats per thread
    if (i >= N_NODES * D / 8) return;
    const float* gp = feat + (size_t)i * 8;
    const float4 a = *(const float4*)gp;
    const float4 b = *(const float4*)(gp + 4);
    bf16x8 h;
    h[0] = (short)f32_to_bf16_rne(a.x); h[1] = (short)f32_to_bf16_rne(a.y);
    h[2] = (short)f32_to_bf16_rne(a.z); h[3] = (short)f32_to_bf16_rne(a.w);
    h[4] = (short)f32_to_bf16_rne(b.x); h[5] = (short)f32_to_bf16_rne(b.y);
    h[6] = (short)f32_to_bf16_rne(b.z); h[7] = (short)f32_to_bf16_rne(b.w);
    *(bf16x8*)&featb[(size_t)i * 8] = h;
}

// ---------------- S1: per-wg bucket histogram ----------------
__launch_bounds__(256)
__global__ void s1_hist_kernel(const int* __restrict__ dst, int* __restrict__ ghist) {
    __shared__ int hist[256];
    const int t = threadIdx.x;
    const int w = blockIdx.x;
    hist[t] = 0;
    __syncthreads();
    const int base = w * EPW;
    for (int i = t; i < EPW; i += 256)
        atomicAdd(&hist[dst[base + i] >> 8], 1);
    __syncthreads();
    ghist[w * 256 + t] = hist[t];
}

// ---------------- S2: bucket scan -> gboff, per-(wg,bucket) cursors gpos ----------------
__launch_bounds__(256)
__global__ void s2_scan_kernel(const int* __restrict__ ghist,
                               int* __restrict__ gpos,
                               int* __restrict__ gboff) {
    __shared__ int s[256];
    const int b = threadIdx.x;
    int tot = 0;
    for (int w = 0; w < NWG; ++w) tot += ghist[w * 256 + b];
    s[b] = tot;
    __syncthreads();
    for (int d = 1; d < 256; d <<= 1) {
        int v = 0;
        if (b >= d) v = s[b - d];
        __syncthreads();
        s[b] += v;
        __syncthreads();
    }
    const int boff = s[b] - tot;   // exclusive
    gboff[b] = boff;
    if (b == 255) gboff[256] = s[255];
    int run = boff;
    for (int w = 0; w < NWG; ++w) {
        gpos[w * 256 + b] = run;
        run += ghist[w * 256 + b];
    }
}

// ---------------- S3: bin edges into bucket-major (src,dst) pairs ----------------
__launch_bounds__(256)
__global__ void s3_bin_kernel(const int* __restrict__ src,
                              const int* __restrict__ dst,
                              const int* __restrict__ gpos,
                              uint2* __restrict__ binned) {
    __shared__ int cur[256];
    const int t = threadIdx.x;
    const int w = blockIdx.x;
    cur[t] = gpos[w * 256 + t];
    __syncthreads();
    const int base = w * EPW;
    for (int i = t; i < EPW; i += 256) {
        const int s = src[base + i];
        const int d = dst[base + i];
        const int p = atomicAdd(&cur[d >> 8], 1);
        binned[p] = make_uint2((unsigned)s, (unsigned)d);
    }
}

// ---------------- finalize: per-bucket degree + intra-bucket scan + CSR scatter ----------------
// CSR is bucket-major, so node's global offset = gboff[b] + intra-bucket exclusive scan.
__launch_bounds__(256)
__global__ void finalize_kernel(const uint2* __restrict__ binned,
                                const int* __restrict__ gboff,
                                int* __restrict__ deg_i,
                                int* __restrict__ off,
                                int* __restrict__ csr_src) {
    __shared__ int c0[256];
    __shared__ int s[256];
    __shared__ int cur[256];
    const int t = threadIdx.x;
    const int b = blockIdx.x;
    c0[t] = 0;
    __syncthreads();
    const int lo = gboff[b], hi = gboff[b + 1];
    for (int i = lo + t; i < hi; i += 256)
        atomicAdd(&c0[binned[i].y & 255u], 1);
    __syncthreads();
    const int c = c0[t];
    s[t] = c;
    __syncthreads();
    for (int d = 1; d < 256; d <<= 1) {
        int v = 0;
        if (t >= d) v = s[t - d];
        __syncthreads();
        s[t] += v;
        __syncthreads();
    }
    const int o = gboff[b] + s[t] - c;   // global CSR offset for this node
    const int node = b * 256 + t;
    if (node < N_NODES) {
        deg_i[node] = c;
        off[node] = o;
    }
    cur[t] = o;
    __syncthreads();
    for (int i = lo + t; i < hi; i += 256) {
        const uint2 u = binned[i];
        const int p = atomicAdd(&cur[u.y & 255u], 1);
        csr_src[p] = (int)u.x;
    }
}

// ---------------- gather-aggregate: 32 lanes/row, 2 nodes per wave, bf16 out ----------------
__launch_bounds__(256)
__global__ void gather_kernel(const unsigned short* __restrict__ featb,
                              const int* __restrict__ off,
                              const int* __restrict__ deg_i,
                              const int* __restrict__ csr_src,
                              unsigned short* __restrict__ hneighb) {
    const int t = threadIdx.x;
    const int lane4 = (t & 31) * 4;                 // feature base: 4 bf16 per lane
    const int node = blockIdx.x * 8 + (t >> 5);     // 8 nodes per 256-thread block
    if (node >= N_NODES) return;
    const int s0 = off[node];
    const int cnt = deg_i[node];
    float a0 = 0.f, a1 = 0.f, a2 = 0.f, a3 = 0.f;
    int e = s0;
    const int e4 = s0 + (cnt & ~3);
    for (; e < e4; e += 4) {
        const int i0 = csr_src[e];
        const int i1 = csr_src[e + 1];
        const int i2 = csr_src[e + 2];
        const int i3 = csr_src[e + 3];
        const uint2 u0 = *(const uint2*)&featb[(size_t)i0 * D + lane4];
        const uint2 u1 = *(const uint2*)&featb[(size_t)i1 * D + lane4];
        const uint2 u2 = *(const uint2*)&featb[(size_t)i2 * D + lane4];
        const uint2 u3 = *(const uint2*)&featb[(size_t)i3 * D + lane4];
        a0 += bf16lo_f32(u0.x); a1 += bf16hi_f32(u0.x); a2 += bf16lo_f32(u0.y); a3 += bf16hi_f32(u0.y);
        a0 += bf16lo_f32(u1.x); a1 += bf16hi_f32(u1.x); a2 += bf16lo_f32(u1.y); a3 += bf16hi_f32(u1.y);
        a0 += bf16lo_f32(u2.x); a1 += bf16hi_f32(u2.x); a2 += bf16lo_f32(u2.y); a3 += bf16hi_f32(u2.y);
        a0 += bf16lo_f32(u3.x); a1 += bf16hi_f32(u3.x); a2 += bf16lo_f32(u3.y); a3 += bf16hi_f32(u3.y);
    }
    for (; e < s0 + cnt; ++e) {
        const uint2 u = *(const uint2*)&featb[(size_t)csr_src[e] * D + lane4];
        a0 += bf16lo_f32(u.x); a1 += bf16hi_f32(u.x); a2 += bf16lo_f32(u.y); a3 += bf16hi_f32(u.y);
    }
    const float sc = 1.f / fmaxf((float)cnt, 1.f);
    const unsigned h0 = f32_to_bf16_rne(a0 * sc);
    const unsigned h1 = f32_to_bf16_rne(a1 * sc);
    const unsigned h2 = f32_to_bf16_rne(a2 * sc);
    const unsigned h3 = f32_to_bf16_rne(a3 * sc);
    *(uint2*)&hneighb[(size_t)node * D + lane4] = make_uint2((h1 << 16) | h0, (h3 << 16) | h2);
}

// ---------------- W -> bf16 MFMA-fragment-linear layout (hi only) ----------------
__global__ void wsplit_kernel(const float* __restrict__ Wself,
                              const float* __restrict__ Wneigh,
                              unsigned short* __restrict__ Wf) {
    const int unit = blockIdx.x * 256 + threadIdx.x;
    if (unit >= 4096) return;
    const int phase = unit >> 11;        // 0..1
    const int kbi   = (unit >> 9) & 3;   // 0..3
    const int u     = unit & 511;
    const int j     = u & 127;
    const int c     = u >> 7;            // 0..3
    const float* __restrict__ W = phase ? Wneigh : Wself;
    const float* gp = &W[(size_t)j * D + kbi * 32 + c * 8];
    const int p = j >> 5, ks = c >> 1, g = c & 1;
    const size_t base = (size_t)(phase * 4 + kbi) * 4096
                      + (size_t)(((p * 2 + ks) * 64) + (j & 31) + 32 * g) * 8;
#pragma unroll
    for (int e = 0; e < 8; ++e)
        Wf[base + e] = f32_to_bf16_rne(gp[e]);
}

// ---------------- MFMA GEMM, pure bf16 ----------------
// out[n][j] = feat_b[n,:]·Wself_b[j,:] + hneigh_b[n,:]·Wneigh_b[j,:] + b[j]
__launch_bounds__(256)
__global__ void gemm_kernel(const unsigned short* __restrict__ featb,
                            const unsigned short* __restrict__ hneighb,
                            const unsigned short* __restrict__ Wf,
                            const float* __restrict__ bias,
                            float* __restrict__ out) {
    __shared__ __align__(16) unsigned short sA[4096];
    __shared__ __align__(16) unsigned short sW[4096];

    const int tid  = threadIdx.x;
    const int wv   = tid >> 6;   // wave 0..3 -> A panel (rows wv*32..wv*32+31)
    const int l    = tid & 63;
    const int row0 = blockIdx.x * 128;

    f32x16 acc[4] = {};

#pragma unroll 1
    for (int blk = 0; blk < 8; ++blk) {
        const int kbi = blk & 3;
        const unsigned short* __restrict__ A = (blk < 4) ? featb : hneighb;

        __syncthreads();   // previous MFMA reads done before overwrite

        // ---- stage W (frag-layout in global): contiguous copy ----
        {
            const size_t gbase = (size_t)blk * 4096;
#pragma unroll
            for (int i = 0; i < 2; ++i) {
                const int o = (i * 256 + tid) * 8;
                *(bf16x8*)&sW[o] = *(const bf16x8*)&Wf[gbase + o];
            }
        }
        // ---- stage A: bf16 copy into frag-linear LDS ----
#pragma unroll
        for (int i = 0; i < 2; ++i) {
            const int u   = i * 256 + tid;   // 0..511 = 128 rows x 4 chunks
            const int row = u & 127;
            const int c   = u >> 7;          // 8-k chunk within the 32-k block
            const int grow = row0 + row;
            bf16x8 v = {};
            if (grow < N_NODES)
                v = *(const bf16x8*)&A[(size_t)grow * D + kbi * 32 + c * 8];
            const int p = row >> 5, ks = c >> 1, g = c & 1;
            const int o = ((p * 2 + ks) * 64 + (row & 31) + 32 * g) * 8;
            *(bf16x8*)&sA[o] = v;
        }
        __syncthreads();

        // ---- MFMA: 2 k-steps of 16, 4 MFMA each ----
#pragma unroll
        for (int ks = 0; ks < 2; ++ks) {
            const bf16x8 a = *(const bf16x8*)&sA[((wv * 2 + ks) * 64 + l) * 8];
#pragma unroll
            for (int n = 0; n < 4; ++n) {
                const bf16x8 w = *(const bf16x8*)&sW[((n * 2 + ks) * 64 + l) * 8];
                acc[n] = __builtin_amdgcn_mfma_f32_32x32x16_bf16(a, w, acc[n], 0, 0, 0);
            }
        }
    }

    // ---- epilogue: C/D layout col=l&31, row=(r&3)+8*(r>>2)+4*(l>>5) ----
    const int col = l & 31;
    const int hi2 = l >> 5;
    float bv[4];
#pragma unroll
    for (int n = 0; n < 4; ++n) bv[n] = bias[n * 32 + col];
#pragma unroll
    for (int r = 0; r < 16; ++r) {
        const int rloc = (r & 3) + 8 * (r >> 2) + 4 * hi2;
        const int grow = row0 + wv * 32 + rloc;
        if (grow < N_NODES) {
#pragma unroll
            for (int n = 0; n < 4; ++n)
                out[(size_t)grow * D + n * 32 + col] = acc[n][r] + bv[n];
        }
    }
}

extern "C" void kernel_launch(void* const* d_in, const int* in_sizes, int n_in,
                              void* d_out, int out_size, void* d_ws, size_t ws_size,
                              hipStream_t stream) {
    const float* feat  = (const float*)d_in[0];
    const float* Wn    = (const float*)d_in[1];  // W_neigh
    const float* Wsf   = (const float*)d_in[2];  // W_self
    const float* bself = (const float*)d_in[3];
    const int*   src   = (const int*)d_in[4];
    const int*   dst   = (const int*)d_in[5];
    float* out = (float*)d_out;

    // workspace layout
    unsigned short* featb   = (unsigned short*)d_ws;               // N*D bf16
    unsigned short* hneighb = featb + (size_t)N_NODES * D;         // N*D bf16
    uint2* binned    = (uint2*)(hneighb + (size_t)N_NODES * D);    // E uint2
    int*   csr_src   = (int*)(binned + N_EDGES);                   // E ints
    int*   deg_i     = csr_src + N_EDGES;                          // N ints
    int*   off       = deg_i + N_NODES;                            // N ints
    int*   ghist     = off + N_NODES;                              // NWG*256 ints
    int*   gpos      = ghist + NWG * 256;                          // NWG*256 ints
    int*   gboff     = gpos + NWG * 256;                           // 257 ints (pad 260)
    unsigned short* Wf = (unsigned short*)(gboff + 260);           // 8*4096 bf16

    fconv_kernel<<<(N_NODES * D / 8 + 255) / 256, 256, 0, stream>>>(feat, featb);
    s1_hist_kernel<<<NWG, 256, 0, stream>>>(dst, ghist);
    s2_scan_kernel<<<1, 256, 0, stream>>>(ghist, gpos, gboff);
    s3_bin_kernel<<<NWG, 256, 0, stream>>>(src, dst, gpos, binned);
    finalize_kernel<<<NBUCK, 256, 0, stream>>>(binned, gboff, deg_i, off, csr_src);
    wsplit_kernel<<<16, 256, 0, stream>>>(Wsf, Wn, Wf);
    gather_kernel<<<(N_NODES + 7) / 8, 256, 0, stream>>>(featb, off, deg_i, csr_src, hneighb);

    const int gblocks = (N_NODES + 127) / 128;   // 391
    gemm_kernel<<<gblocks, 256, 0, stream>>>(featb, hneighb, Wf, bself, out);
}

// Round 7
// 96.324 us; speedup vs baseline: 5.8384x; 1.0278x over previous
//
#include <hip/hip_runtime.h>
#include <cstddef>
#include <cstdint>

#define N_NODES 50000
#define N_EDGES 800000
#define D 128
#define NWG 128                            // binning workgroups
#define EPW (N_EDGES / NWG)                // 6250 edges per wg
#define NBUCK 196                          // ceil(50000/256)

typedef __attribute__((ext_vector_type(8))) short bf16x8;
typedef __attribute__((ext_vector_type(16))) float f32x16;

__device__ __forceinline__ unsigned short f32_to_bf16_rne(float x) {
    unsigned u = __builtin_bit_cast(unsigned, x);
    unsigned r = (u + 0x7FFFu + ((u >> 16) & 1u)) >> 16;
    return (unsigned short)r;
}
__device__ __forceinline__ float bf16lo_f32(unsigned u) {
    return __builtin_bit_cast(float, u << 16);
}
__device__ __forceinline__ float bf16hi_f32(unsigned u) {
    return __builtin_bit_cast(float, u & 0xFFFF0000u);
}

// ---------------- feat f32 -> bf16 row table ----------------
__launch_bounds__(256)
__global__ void fconv_kernel(const float* __restrict__ feat,
                             unsigned short* __restrict__ featb) {
    const int i = blockIdx.x * 256 + threadIdx.x;   // 8 floats per thread
    if (i >= N_NODES * D / 8) return;
    const float* gp = feat + (size_t)i * 8;
    const float4 a = *(const float4*)gp;
    const float4 b = *(const float4*)(gp + 4);
    bf16x8 h;
    h[0] = (short)f32_to_bf16_rne(a.x); h[1] = (short)f32_to_bf16_rne(a.y);
    h[2] = (short)f32_to_bf16_rne(a.z); h[3] = (short)f32_to_bf16_rne(a.w);
    h[4] = (short)f32_to_bf16_rne(b.x); h[5] = (short)f32_to_bf16_rne(b.y);
    h[6] = (short)f32_to_bf16_rne(b.z); h[7] = (short)f32_to_bf16_rne(b.w);
    *(bf16x8*)&featb[(size_t)i * 8] = h;
}

// ---------------- S1: per-wg bucket histogram ----------------
__launch_bounds__(256)
__global__ void s1_hist_kernel(const int* __restrict__ dst, int* __restrict__ ghist) {
    __shared__ int hist[256];
    const int t = threadIdx.x;
    const int w = blockIdx.x;
    hist[t] = 0;
    __syncthreads();
    const int base = w * EPW;
    for (int i = t; i < EPW; i += 256)
        atomicAdd(&hist[dst[base + i] >> 8], 1);
    __syncthreads();
    ghist[w * 256 + t] = hist[t];
}

// ---------------- S2: bucket scan -> gboff, per-(wg,bucket) cursors gpos ----------------
__launch_bounds__(256)
__global__ void s2_scan_kernel(const int* __restrict__ ghist,
                               int* __restrict__ gpos,
                               int* __restrict__ gboff) {
    __shared__ int s[256];
    const int b = threadIdx.x;
    int tot = 0;
    for (int w = 0; w < NWG; ++w) tot += ghist[w * 256 + b];
    s[b] = tot;
    __syncthreads();
    for (int d = 1; d < 256; d <<= 1) {
        int v = 0;
        if (b >= d) v = s[b - d];
        __syncthreads();
        s[b] += v;
        __syncthreads();
    }
    const int boff = s[b] - tot;   // exclusive
    gboff[b] = boff;
    if (b == 255) gboff[256] = s[255];
    int run = boff;
    for (int w = 0; w < NWG; ++w) {
        gpos[w * 256 + b] = run;
        run += ghist[w * 256 + b];
    }
}

// ---------------- S3: bin edges, packed (src:16 | dst&255:8) ----------------
__launch_bounds__(256)
__global__ void s3_bin_kernel(const int* __restrict__ src,
                              const int* __restrict__ dst,
                              const int* __restrict__ gpos,
                              unsigned* __restrict__ binned) {
    __shared__ int cur[256];
    const int t = threadIdx.x;
    const int w = blockIdx.x;
    cur[t] = gpos[w * 256 + t];
    __syncthreads();
    const int base = w * EPW;
    for (int i = t; i < EPW; i += 256) {
        const int s = src[base + i];
        const int d = dst[base + i];
        const int p = atomicAdd(&cur[d >> 8], 1);
        binned[p] = (unsigned)s | ((unsigned)(d & 255) << 16);
    }
}

// ---------------- finalize: per-bucket degree + intra-bucket scan + CSR scatter ----------------
__launch_bounds__(256)
__global__ void finalize_kernel(const unsigned* __restrict__ binned,
                                const int* __restrict__ gboff,
                                int* __restrict__ deg_i,
                                int* __restrict__ off,
                                unsigned short* __restrict__ csr_src) {
    __shared__ int c0[256];
    __shared__ int s[256];
    __shared__ int cur[256];
    const int t = threadIdx.x;
    const int b = blockIdx.x;
    c0[t] = 0;
    __syncthreads();
    const int lo = gboff[b], hi = gboff[b + 1];
    for (int i = lo + t; i < hi; i += 256)
        atomicAdd(&c0[(binned[i] >> 16) & 255u], 1);
    __syncthreads();
    const int c = c0[t];
    s[t] = c;
    __syncthreads();
    for (int d = 1; d < 256; d <<= 1) {
        int v = 0;
        if (t >= d) v = s[t - d];
        __syncthreads();
        s[t] += v;
        __syncthreads();
    }
    const int o = gboff[b] + s[t] - c;   // global CSR offset for this node
    const int node = b * 256 + t;
    if (node < N_NODES) {
        deg_i[node] = c;
        off[node] = o;
    }
    cur[t] = o;
    __syncthreads();
    for (int i = lo + t; i < hi; i += 256) {
        const unsigned u = binned[i];
        const int p = atomicAdd(&cur[(u >> 16) & 255u], 1);
        csr_src[p] = (unsigned short)(u & 0xFFFFu);
    }
}

// ---------------- gather-aggregate: 16 lanes/row, 4 nodes/wave, uint4 loads ----------------
__launch_bounds__(256)
__global__ void gather_kernel(const unsigned short* __restrict__ featb,
                              const int* __restrict__ off,
                              const int* __restrict__ deg_i,
                              const unsigned short* __restrict__ csr_src,
                              unsigned short* __restrict__ hneighb) {
    const int t = threadIdx.x;
    const int lane8 = (t & 15) * 8;                 // feature base: 8 bf16 per lane
    const int node = blockIdx.x * 16 + (t >> 4);    // 16 nodes per 256-thread block
    if (node >= N_NODES) return;
    const int s0 = off[node];
    const int cnt = deg_i[node];
    float a0 = 0.f, a1 = 0.f, a2 = 0.f, a3 = 0.f;
    float a4 = 0.f, a5 = 0.f, a6 = 0.f, a7 = 0.f;
    int e = s0;
    const int e4 = s0 + (cnt & ~3);
#define ACC(u) { a0 += bf16lo_f32((u).x); a1 += bf16hi_f32((u).x); \
                 a2 += bf16lo_f32((u).y); a3 += bf16hi_f32((u).y); \
                 a4 += bf16lo_f32((u).z); a5 += bf16hi_f32((u).z); \
                 a6 += bf16lo_f32((u).w); a7 += bf16hi_f32((u).w); }
    for (; e < e4; e += 4) {
        const int i0 = csr_src[e];
        const int i1 = csr_src[e + 1];
        const int i2 = csr_src[e + 2];
        const int i3 = csr_src[e + 3];
        const uint4 u0 = *(const uint4*)&featb[(size_t)i0 * D + lane8];
        const uint4 u1 = *(const uint4*)&featb[(size_t)i1 * D + lane8];
        const uint4 u2 = *(const uint4*)&featb[(size_t)i2 * D + lane8];
        const uint4 u3 = *(const uint4*)&featb[(size_t)i3 * D + lane8];
        ACC(u0); ACC(u1); ACC(u2); ACC(u3);
    }
    for (; e < s0 + cnt; ++e) {
        const uint4 u = *(const uint4*)&featb[(size_t)csr_src[e] * D + lane8];
        ACC(u);
    }
#undef ACC
    const float sc = 1.f / fmaxf((float)cnt, 1.f);
    const unsigned h0 = f32_to_bf16_rne(a0 * sc);
    const unsigned h1 = f32_to_bf16_rne(a1 * sc);
    const unsigned h2 = f32_to_bf16_rne(a2 * sc);
    const unsigned h3 = f32_to_bf16_rne(a3 * sc);
    const unsigned h4 = f32_to_bf16_rne(a4 * sc);
    const unsigned h5 = f32_to_bf16_rne(a5 * sc);
    const unsigned h6 = f32_to_bf16_rne(a6 * sc);
    const unsigned h7 = f32_to_bf16_rne(a7 * sc);
    uint4 o;
    o.x = (h1 << 16) | h0;
    o.y = (h3 << 16) | h2;
    o.z = (h5 << 16) | h4;
    o.w = (h7 << 16) | h6;
    *(uint4*)&hneighb[(size_t)node * D + lane8] = o;
}

// ---------------- W -> bf16 MFMA-fragment-linear layout ----------------
__global__ void wsplit_kernel(const float* __restrict__ Wself,
                              const float* __restrict__ Wneigh,
                              unsigned short* __restrict__ Wf) {
    const int unit = blockIdx.x * 256 + threadIdx.x;
    if (unit >= 4096) return;
    const int phase = unit >> 11;        // 0..1
    const int kbi   = (unit >> 9) & 3;   // 0..3
    const int u     = unit & 511;
    const int j     = u & 127;
    const int c     = u >> 7;            // 0..3
    const float* __restrict__ W = phase ? Wneigh : Wself;
    const float* gp = &W[(size_t)j * D + kbi * 32 + c * 8];
    const int p = j >> 5, ks = c >> 1, g = c & 1;
    const size_t base = (size_t)(phase * 4 + kbi) * 4096
                      + (size_t)(((p * 2 + ks) * 64) + (j & 31) + 32 * g) * 8;
#pragma unroll
    for (int e = 0; e < 8; ++e)
        Wf[base + e] = f32_to_bf16_rne(gp[e]);
}

// ---------------- MFMA GEMM, pure bf16 ----------------
__launch_bounds__(256)
__global__ void gemm_kernel(const unsigned short* __restrict__ featb,
                            const unsigned short* __restrict__ hneighb,
                            const unsigned short* __restrict__ Wf,
                            const float* __restrict__ bias,
                            float* __restrict__ out) {
    __shared__ __align__(16) unsigned short sA[4096];
    __shared__ __align__(16) unsigned short sW[4096];

    const int tid  = threadIdx.x;
    const int wv   = tid >> 6;   // wave 0..3 -> A panel (rows wv*32..wv*32+31)
    const int l    = tid & 63;
    const int row0 = blockIdx.x * 128;

    f32x16 acc[4] = {};

#pragma unroll 1
    for (int blk = 0; blk < 8; ++blk) {
        const int kbi = blk & 3;
        const unsigned short* __restrict__ A = (blk < 4) ? featb : hneighb;

        __syncthreads();   // previous MFMA reads done before overwrite

        // ---- stage W (frag-layout in global): contiguous copy ----
        {
            const size_t gbase = (size_t)blk * 4096;
#pragma unroll
            for (int i = 0; i < 2; ++i) {
                const int o = (i * 256 + tid) * 8;
                *(bf16x8*)&sW[o] = *(const bf16x8*)&Wf[gbase + o];
            }
        }
        // ---- stage A: bf16 copy into frag-linear LDS ----
#pragma unroll
        for (int i = 0; i < 2; ++i) {
            const int u   = i * 256 + tid;   // 0..511 = 128 rows x 4 chunks
            const int row = u & 127;
            const int c   = u >> 7;          // 8-k chunk within the 32-k block
            const int grow = row0 + row;
            bf16x8 v = {};
            if (grow < N_NODES)
                v = *(const bf16x8*)&A[(size_t)grow * D + kbi * 32 + c * 8];
            const int p = row >> 5, ks = c >> 1, g = c & 1;
            const int o = ((p * 2 + ks) * 64 + (row & 31) + 32 * g) * 8;
            *(bf16x8*)&sA[o] = v;
        }
        __syncthreads();

        // ---- MFMA: 2 k-steps of 16, 4 MFMA each ----
#pragma unroll
        for (int ks = 0; ks < 2; ++ks) {
            const bf16x8 a = *(const bf16x8*)&sA[((wv * 2 + ks) * 64 + l) * 8];
#pragma unroll
            for (int n = 0; n < 4; ++n) {
                const bf16x8 w = *(const bf16x8*)&sW[((n * 2 + ks) * 64 + l) * 8];
                acc[n] = __builtin_amdgcn_mfma_f32_32x32x16_bf16(a, w, acc[n], 0, 0, 0);
            }
        }
    }

    // ---- epilogue: C/D layout col=l&31, row=(r&3)+8*(r>>2)+4*(l>>5) ----
    const int col = l & 31;
    const int hi2 = l >> 5;
    float bv[4];
#pragma unroll
    for (int n = 0; n < 4; ++n) bv[n] = bias[n * 32 + col];
#pragma unroll
    for (int r = 0; r < 16; ++r) {
        const int rloc = (r & 3) + 8 * (r >> 2) + 4 * hi2;
        const int grow = row0 + wv * 32 + rloc;
        if (grow < N_NODES) {
#pragma unroll
            for (int n = 0; n < 4; ++n)
                out[(size_t)grow * D + n * 32 + col] = acc[n][r] + bv[n];
        }
    }
}

extern "C" void kernel_launch(void* const* d_in, const int* in_sizes, int n_in,
                              void* d_out, int out_size, void* d_ws, size_t ws_size,
                              hipStream_t stream) {
    const float* feat  = (const float*)d_in[0];
    const float* Wn    = (const float*)d_in[1];  // W_neigh
    const float* Wsf   = (const float*)d_in[2];  // W_self
    const float* bself = (const float*)d_in[3];
    const int*   src   = (const int*)d_in[4];
    const int*   dst   = (const int*)d_in[5];
    float* out = (float*)d_out;

    // workspace layout
    unsigned short* featb   = (unsigned short*)d_ws;               // N*D bf16
    unsigned short* hneighb = featb + (size_t)N_NODES * D;         // N*D bf16
    unsigned* binned = (unsigned*)(hneighb + (size_t)N_NODES * D); // E uint (packed)
    unsigned short* csr_src = (unsigned short*)(binned + N_EDGES); // E ushort
    int*   deg_i     = (int*)(csr_src + N_EDGES);                  // N ints
    int*   off       = deg_i + N_NODES;                            // N ints
    int*   ghist     = off + N_NODES;                              // NWG*256 ints
    int*   gpos      = ghist + NWG * 256;                          // NWG*256 ints
    int*   gboff     = gpos + NWG * 256;                           // 257 ints (pad 260)
    unsigned short* Wf = (unsigned short*)(gboff + 260);           // 8*4096 bf16

    fconv_kernel<<<(N_NODES * D / 8 + 255) / 256, 256, 0, stream>>>(feat, featb);
    s1_hist_kernel<<<NWG, 256, 0, stream>>>(dst, ghist);
    s2_scan_kernel<<<1, 256, 0, stream>>>(ghist, gpos, gboff);
    s3_bin_kernel<<<NWG, 256, 0, stream>>>(src, dst, gpos, binned);
    finalize_kernel<<<NBUCK, 256, 0, stream>>>(binned, gboff, deg_i, off, csr_src);
    wsplit_kernel<<<16, 256, 0, stream>>>(Wsf, Wn, Wf);
    gather_kernel<<<(N_NODES + 15) / 16, 256, 0, stream>>>(featb, off, deg_i, csr_src, hneighb);

    const int gblocks = (N_NODES + 127) / 128;   // 391
    gemm_kernel<<<gblocks, 256, 0, stream>>>(featb, hneighb, Wf, bself, out);
}

// Round 8
// 89.913 us; speedup vs baseline: 6.2547x; 1.0713x over previous
//
#include <hip/hip_runtime.h>
#include <cstddef>
#include <cstdint>

#define N_NODES 50000
#define N_EDGES 800000
#define D 128
#define NWG 128                            // binning workgroups
#define EPW (N_EDGES / NWG)                // 6250 edges per wg
#define NBUCK 196                          // ceil(50000/256)
#define FCONV_BLKS 3125                    // N*D/8/256
#define WSPLIT_BLKS 16

typedef __attribute__((ext_vector_type(8))) short bf16x8;
typedef __attribute__((ext_vector_type(16))) float f32x16;

__device__ __forceinline__ unsigned short f32_to_bf16_rne(float x) {
    unsigned u = __builtin_bit_cast(unsigned, x);
    unsigned r = (u + 0x7FFFu + ((u >> 16) & 1u)) >> 16;
    return (unsigned short)r;
}
__device__ __forceinline__ float bf16lo_f32(unsigned u) {
    return __builtin_bit_cast(float, u << 16);
}
__device__ __forceinline__ float bf16hi_f32(unsigned u) {
    return __builtin_bit_cast(float, u & 0xFFFF0000u);
}

// ---------------- prep: fconv | wsplit | s1 histogram, one launch ----------------
__launch_bounds__(256)
__global__ void prep_kernel(const float* __restrict__ feat,
                            const float* __restrict__ Wself,
                            const float* __restrict__ Wneigh,
                            const int* __restrict__ dst,
                            unsigned short* __restrict__ featb,
                            unsigned short* __restrict__ Wf,
                            int* __restrict__ ghist) {
    __shared__ int hist[256];
    const int bid = blockIdx.x;
    const int t = threadIdx.x;
    if (bid < FCONV_BLKS) {
        // ---- fconv: feat f32 -> bf16 rows ----
        const int i = bid * 256 + t;   // 8 floats per thread
        if (i >= N_NODES * D / 8) return;
        const float* gp = feat + (size_t)i * 8;
        const float4 a = *(const float4*)gp;
        const float4 b = *(const float4*)(gp + 4);
        bf16x8 h;
        h[0] = (short)f32_to_bf16_rne(a.x); h[1] = (short)f32_to_bf16_rne(a.y);
        h[2] = (short)f32_to_bf16_rne(a.z); h[3] = (short)f32_to_bf16_rne(a.w);
        h[4] = (short)f32_to_bf16_rne(b.x); h[5] = (short)f32_to_bf16_rne(b.y);
        h[6] = (short)f32_to_bf16_rne(b.z); h[7] = (short)f32_to_bf16_rne(b.w);
        *(bf16x8*)&featb[(size_t)i * 8] = h;
    } else if (bid < FCONV_BLKS + WSPLIT_BLKS) {
        // ---- wsplit: W -> bf16 MFMA-fragment-linear layout ----
        const int unit = (bid - FCONV_BLKS) * 256 + t;
        if (unit >= 4096) return;
        const int phase = unit >> 11;        // 0..1
        const int kbi   = (unit >> 9) & 3;   // 0..3
        const int u     = unit & 511;
        const int j     = u & 127;
        const int c     = u >> 7;            // 0..3
        const float* __restrict__ W = phase ? Wneigh : Wself;
        const float* gp = &W[(size_t)j * D + kbi * 32 + c * 8];
        const int p = j >> 5, ks = c >> 1, g = c & 1;
        const size_t base = (size_t)(phase * 4 + kbi) * 4096
                          + (size_t)(((p * 2 + ks) * 64) + (j & 31) + 32 * g) * 8;
#pragma unroll
        for (int e = 0; e < 8; ++e)
            Wf[base + e] = f32_to_bf16_rne(gp[e]);
    } else {
        // ---- s1: per-wg bucket histogram ----
        const int w = bid - FCONV_BLKS - WSPLIT_BLKS;
        hist[t] = 0;
        __syncthreads();
        const int base = w * EPW;
        for (int i = t; i < EPW; i += 256)
            atomicAdd(&hist[dst[base + i] >> 8], 1);
        __syncthreads();
        ghist[w * 256 + t] = hist[t];
    }
}

// ---------------- S3 (with inline S2): scan ghist + bin edges packed ----------------
__launch_bounds__(256)
__global__ void s3_bin_kernel(const int* __restrict__ src,
                              const int* __restrict__ dst,
                              const int* __restrict__ ghist,
                              unsigned* __restrict__ binned,
                              int* __restrict__ gboff) {
    __shared__ int s[256];
    __shared__ int cur[256];
    const int t = threadIdx.x;
    const int w = blockIdx.x;
    // per-bucket totals + my prefix across wgs
    int tot = 0, mypre = 0;
    for (int w2 = 0; w2 < NWG; ++w2) {
        const int v = ghist[w2 * 256 + t];
        tot += v;
        if (w2 < w) mypre += v;
    }
    s[t] = tot;
    __syncthreads();
    for (int d = 1; d < 256; d <<= 1) {
        int v = 0;
        if (t >= d) v = s[t - d];
        __syncthreads();
        s[t] += v;
        __syncthreads();
    }
    const int boff = s[t] - tot;   // exclusive bucket offset
    if (w == 0) {
        gboff[t] = boff;
        if (t == 255) gboff[256] = s[255];
    }
    cur[t] = boff + mypre;
    __syncthreads();
    const int base = w * EPW;
    for (int i = t; i < EPW; i += 256) {
        const int sv = src[base + i];
        const int d = dst[base + i];
        const int p = atomicAdd(&cur[d >> 8], 1);
        binned[p] = (unsigned)sv | ((unsigned)(d & 255) << 16);
    }
}

// ---------------- finalize: per-bucket degree + intra-bucket scan + CSR scatter ----------------
__launch_bounds__(256)
__global__ void finalize_kernel(const unsigned* __restrict__ binned,
                                const int* __restrict__ gboff,
                                int* __restrict__ deg_i,
                                int* __restrict__ off,
                                unsigned short* __restrict__ csr_src) {
    __shared__ int c0[256];
    __shared__ int s[256];
    __shared__ int cur[256];
    const int t = threadIdx.x;
    const int b = blockIdx.x;
    c0[t] = 0;
    __syncthreads();
    const int lo = gboff[b], hi = gboff[b + 1];
    for (int i = lo + t; i < hi; i += 256)
        atomicAdd(&c0[(binned[i] >> 16) & 255u], 1);
    __syncthreads();
    const int c = c0[t];
    s[t] = c;
    __syncthreads();
    for (int d = 1; d < 256; d <<= 1) {
        int v = 0;
        if (t >= d) v = s[t - d];
        __syncthreads();
        s[t] += v;
        __syncthreads();
    }
    const int o = gboff[b] + s[t] - c;   // global CSR offset for this node
    const int node = b * 256 + t;
    if (node < N_NODES) {
        deg_i[node] = c;
        off[node] = o;
    }
    cur[t] = o;
    __syncthreads();
    for (int i = lo + t; i < hi; i += 256) {
        const unsigned u = binned[i];
        const int p = atomicAdd(&cur[(u >> 16) & 255u], 1);
        csr_src[p] = (unsigned short)(u & 0xFFFFu);
    }
}

// ---------------- gather-aggregate: 16 lanes/row, unroll 8, bf16 out ----------------
__launch_bounds__(256)
__global__ void gather_kernel(const unsigned short* __restrict__ featb,
                              const int* __restrict__ off,
                              const int* __restrict__ deg_i,
                              const unsigned short* __restrict__ csr_src,
                              unsigned short* __restrict__ hneighb) {
    const int t = threadIdx.x;
    const int lane8 = (t & 15) * 8;                 // feature base: 8 bf16 per lane
    const int node = blockIdx.x * 16 + (t >> 4);    // 16 nodes per 256-thread block
    if (node >= N_NODES) return;
    const int s0 = off[node];
    const int cnt = deg_i[node];
    const int end = s0 + cnt;
    float a0 = 0.f, a1 = 0.f, a2 = 0.f, a3 = 0.f;
    float a4 = 0.f, a5 = 0.f, a6 = 0.f, a7 = 0.f;
    int e = s0;
#define ACC(u) { a0 += bf16lo_f32((u).x); a1 += bf16hi_f32((u).x); \
                 a2 += bf16lo_f32((u).y); a3 += bf16hi_f32((u).y); \
                 a4 += bf16lo_f32((u).z); a5 += bf16hi_f32((u).z); \
                 a6 += bf16lo_f32((u).w); a7 += bf16hi_f32((u).w); }
    for (; e + 8 <= end; e += 8) {
        const int i0 = csr_src[e];
        const int i1 = csr_src[e + 1];
        const int i2 = csr_src[e + 2];
        const int i3 = csr_src[e + 3];
        const int i4 = csr_src[e + 4];
        const int i5 = csr_src[e + 5];
        const int i6 = csr_src[e + 6];
        const int i7 = csr_src[e + 7];
        const uint4 u0 = *(const uint4*)&featb[(size_t)i0 * D + lane8];
        const uint4 u1 = *(const uint4*)&featb[(size_t)i1 * D + lane8];
        const uint4 u2 = *(const uint4*)&featb[(size_t)i2 * D + lane8];
        const uint4 u3 = *(const uint4*)&featb[(size_t)i3 * D + lane8];
        const uint4 u4 = *(const uint4*)&featb[(size_t)i4 * D + lane8];
        const uint4 u5 = *(const uint4*)&featb[(size_t)i5 * D + lane8];
        const uint4 u6 = *(const uint4*)&featb[(size_t)i6 * D + lane8];
        const uint4 u7 = *(const uint4*)&featb[(size_t)i7 * D + lane8];
        ACC(u0); ACC(u1); ACC(u2); ACC(u3);
        ACC(u4); ACC(u5); ACC(u6); ACC(u7);
    }
    for (; e + 4 <= end; e += 4) {
        const int i0 = csr_src[e];
        const int i1 = csr_src[e + 1];
        const int i2 = csr_src[e + 2];
        const int i3 = csr_src[e + 3];
        const uint4 u0 = *(const uint4*)&featb[(size_t)i0 * D + lane8];
        const uint4 u1 = *(const uint4*)&featb[(size_t)i1 * D + lane8];
        const uint4 u2 = *(const uint4*)&featb[(size_t)i2 * D + lane8];
        const uint4 u3 = *(const uint4*)&featb[(size_t)i3 * D + lane8];
        ACC(u0); ACC(u1); ACC(u2); ACC(u3);
    }
    for (; e < end; ++e) {
        const uint4 u = *(const uint4*)&featb[(size_t)csr_src[e] * D + lane8];
        ACC(u);
    }
#undef ACC
    const float sc = 1.f / fmaxf((float)cnt, 1.f);
    const unsigned h0 = f32_to_bf16_rne(a0 * sc);
    const unsigned h1 = f32_to_bf16_rne(a1 * sc);
    const unsigned h2 = f32_to_bf16_rne(a2 * sc);
    const unsigned h3 = f32_to_bf16_rne(a3 * sc);
    const unsigned h4 = f32_to_bf16_rne(a4 * sc);
    const unsigned h5 = f32_to_bf16_rne(a5 * sc);
    const unsigned h6 = f32_to_bf16_rne(a6 * sc);
    const unsigned h7 = f32_to_bf16_rne(a7 * sc);
    uint4 o;
    o.x = (h1 << 16) | h0;
    o.y = (h3 << 16) | h2;
    o.z = (h5 << 16) | h4;
    o.w = (h7 << 16) | h6;
    *(uint4*)&hneighb[(size_t)node * D + lane8] = o;
}

// ---------------- MFMA GEMM, pure bf16, W resident in LDS ----------------
__launch_bounds__(256)
__global__ void gemm_kernel(const unsigned short* __restrict__ featb,
                            const unsigned short* __restrict__ hneighb,
                            const unsigned short* __restrict__ Wf,
                            const float* __restrict__ bias,
                            float* __restrict__ out) {
    __shared__ __align__(16) unsigned short sW[32768];      // 64 KB: all 8 W chunks
    __shared__ __align__(16) unsigned short sA[2][4096];    // 2 x 8 KB A tiles

    const int tid  = threadIdx.x;
    const int wv   = tid >> 6;   // wave 0..3 -> A panel (rows wv*32..wv*32+31)
    const int l    = tid & 63;
    const int row0 = blockIdx.x * 128;

    // ---- load ALL of W once (64 KB, contiguous) ----
#pragma unroll
    for (int i = 0; i < 16; ++i) {
        const int o = (i * 256 + tid) * 8;
        *(bf16x8*)&sW[o] = *(const bf16x8*)&Wf[o];
    }

    // ---- stage A tile for blk into buffer sel ----
    auto stageA = [&](int sel, int blk) {
        const int kbi = blk & 3;
        const unsigned short* __restrict__ A = (blk < 4) ? featb : hneighb;
#pragma unroll
        for (int i = 0; i < 2; ++i) {
            const int u   = i * 256 + tid;   // 0..511 = 128 rows x 4 chunks
            const int row = u & 127;
            const int c   = u >> 7;          // 8-k chunk within the 32-k block
            const int grow = row0 + row;
            bf16x8 v = {};
            if (grow < N_NODES)
                v = *(const bf16x8*)&A[(size_t)grow * D + kbi * 32 + c * 8];
            const int p = row >> 5, ks = c >> 1, g = c & 1;
            const int o = ((p * 2 + ks) * 64 + (row & 31) + 32 * g) * 8;
            *(bf16x8*)&sA[sel][o] = v;
        }
    };

    f32x16 acc[4] = {};

    stageA(0, 0);
    __syncthreads();
#pragma unroll 1
    for (int blk = 0; blk < 8; ++blk) {
        const int cur = blk & 1;
        if (blk < 7) stageA(cur ^ 1, blk + 1);
        const int wbase = blk * 4096;
#pragma unroll
        for (int ks = 0; ks < 2; ++ks) {
            const bf16x8 a = *(const bf16x8*)&sA[cur][((wv * 2 + ks) * 64 + l) * 8];
#pragma unroll
            for (int n = 0; n < 4; ++n) {
                const bf16x8 w = *(const bf16x8*)&sW[wbase + ((n * 2 + ks) * 64 + l) * 8];
                acc[n] = __builtin_amdgcn_mfma_f32_32x32x16_bf16(a, w, acc[n], 0, 0, 0);
            }
        }
        __syncthreads();
    }

    // ---- epilogue: C/D layout col=l&31, row=(r&3)+8*(r>>2)+4*(l>>5) ----
    const int col = l & 31;
    const int hi2 = l >> 5;
    float bv[4];
#pragma unroll
    for (int n = 0; n < 4; ++n) bv[n] = bias[n * 32 + col];
#pragma unroll
    for (int r = 0; r < 16; ++r) {
        const int rloc = (r & 3) + 8 * (r >> 2) + 4 * hi2;
        const int grow = row0 + wv * 32 + rloc;
        if (grow < N_NODES) {
#pragma unroll
            for (int n = 0; n < 4; ++n)
                out[(size_t)grow * D + n * 32 + col] = acc[n][r] + bv[n];
        }
    }
}

extern "C" void kernel_launch(void* const* d_in, const int* in_sizes, int n_in,
                              void* d_out, int out_size, void* d_ws, size_t ws_size,
                              hipStream_t stream) {
    const float* feat  = (const float*)d_in[0];
    const float* Wn    = (const float*)d_in[1];  // W_neigh
    const float* Wsf   = (const float*)d_in[2];  // W_self
    const float* bself = (const float*)d_in[3];
    const int*   src   = (const int*)d_in[4];
    const int*   dst   = (const int*)d_in[5];
    float* out = (float*)d_out;

    // workspace layout (all sections keep 16B alignment)
    unsigned short* featb   = (unsigned short*)d_ws;               // N*D bf16
    unsigned short* hneighb = featb + (size_t)N_NODES * D;         // N*D bf16
    unsigned* binned = (unsigned*)(hneighb + (size_t)N_NODES * D); // E uint (packed)
    unsigned short* csr_src = (unsigned short*)(binned + N_EDGES); // E ushort
    int*   deg_i     = (int*)(csr_src + N_EDGES);                  // N ints
    int*   off       = deg_i + N_NODES;                            // N ints
    int*   ghist     = off + N_NODES;                              // NWG*256 ints
    int*   gboff     = ghist + NWG * 256;                          // 257 ints (pad 320)
    unsigned short* Wf = (unsigned short*)(gboff + 320);           // 8*4096 bf16

    prep_kernel<<<FCONV_BLKS + WSPLIT_BLKS + NWG, 256, 0, stream>>>(
        feat, Wsf, Wn, dst, featb, Wf, ghist);
    s3_bin_kernel<<<NWG, 256, 0, stream>>>(src, dst, ghist, binned, gboff);
    finalize_kernel<<<NBUCK, 256, 0, stream>>>(binned, gboff, deg_i, off, csr_src);
    gather_kernel<<<(N_NODES + 15) / 16, 256, 0, stream>>>(featb, off, deg_i, csr_src, hneighb);

    const int gblocks = (N_NODES + 127) / 128;   // 391
    gemm_kernel<<<gblocks, 256, 0, stream>>>(featb, hneighb, Wf, bself, out);
}

// Round 10
// 80.826 us; speedup vs baseline: 6.9578x; 1.1124x over previous
//
#include <hip/hip_runtime.h>
#include <hip/hip_fp8.h>
#include <cstddef>
#include <cstdint>

#define N_NODES 50000
#define N_EDGES 800000
#define D 128
#define NWG 128                            // binning workgroups
#define EPW (N_EDGES / NWG)                // 6250 edges per wg
#define NBUCK 196                          // ceil(50000/256)
#define FCONV_BLKS 3125                    // N*D/8/256
#define WSPLIT_BLKS 16

typedef __attribute__((ext_vector_type(8))) short bf16x8;
typedef __attribute__((ext_vector_type(16))) float f32x16;
typedef __attribute__((ext_vector_type(2))) float f32x2;

__device__ __forceinline__ unsigned short f32_to_bf16_rne(float x) {
    unsigned u = __builtin_bit_cast(unsigned, x);
    unsigned r = (u + 0x7FFFu + ((u >> 16) & 1u)) >> 16;
    return (unsigned short)r;
}
__device__ __forceinline__ float bf16lo_f32(unsigned u) {
    return __builtin_bit_cast(float, u << 16);
}
__device__ __forceinline__ float bf16hi_f32(unsigned u) {
    return __builtin_bit_cast(float, u & 0xFFFF0000u);
}

// ---- fp8 e4m3 pack/unpack (HW cvt on gfx950; hip_fp8 fallback) ----
#if __has_builtin(__builtin_amdgcn_cvt_pk_fp8_f32) && __has_builtin(__builtin_amdgcn_cvt_pk_f32_fp8)
__device__ __forceinline__ unsigned fp8x4_pack(float v0, float v1, float v2, float v3) {
    int w = 0;
    w = __builtin_amdgcn_cvt_pk_fp8_f32(v0, v1, w, false);   // bytes 0,1
    w = __builtin_amdgcn_cvt_pk_fp8_f32(v2, v3, w, true);    // bytes 2,3
    return (unsigned)w;
}
__device__ __forceinline__ f32x2 fp8x2_lo(unsigned u) {
    return __builtin_amdgcn_cvt_pk_f32_fp8((int)u, false);   // bytes 0,1 -> .x,.y
}
__device__ __forceinline__ f32x2 fp8x2_hi(unsigned u) {
    return __builtin_amdgcn_cvt_pk_f32_fp8((int)u, true);    // bytes 2,3 -> .x,.y
}
#else
__device__ __forceinline__ unsigned fp8x4_pack(float v0, float v1, float v2, float v3) {
    __hip_fp8_e4m3 a(v0), b(v1), c(v2), d(v3);
    return (unsigned)a.__x | ((unsigned)b.__x << 8) | ((unsigned)c.__x << 16) | ((unsigned)d.__x << 24);
}
__device__ __forceinline__ float fp8_dec(unsigned byte) {
    __hip_fp8_e4m3 h; h.__x = (__hip_fp8_storage_t)byte;
    return (float)h;
}
__device__ __forceinline__ f32x2 fp8x2_lo(unsigned u) {
    f32x2 r; r.x = fp8_dec(u & 255u); r.y = fp8_dec((u >> 8) & 255u); return r;
}
__device__ __forceinline__ f32x2 fp8x2_hi(unsigned u) {
    f32x2 r; r.x = fp8_dec((u >> 16) & 255u); r.y = fp8_dec(u >> 24); return r;
}
#endif

// ---------------- prep: fconv (bf16 + fp8 tables) | wsplit | s1 histogram ----------------
__launch_bounds__(256)
__global__ void prep_kernel(const float* __restrict__ feat,
                            const float* __restrict__ Wself,
                            const float* __restrict__ Wneigh,
                            const int* __restrict__ dst,
                            unsigned short* __restrict__ featb,
                            unsigned char* __restrict__ feat8,
                            unsigned short* __restrict__ Wf,
                            int* __restrict__ ghist) {
    __shared__ int hist[256];
    const int bid = blockIdx.x;
    const int t = threadIdx.x;
    if (bid < FCONV_BLKS) {
        // ---- fconv: feat f32 -> bf16 row table + fp8 row table ----
        const int i = bid * 256 + t;   // 8 floats per thread, exact coverage
        if (i >= N_NODES * D / 8) return;
        const float* gp = feat + (size_t)i * 8;
        const float4 a = *(const float4*)gp;
        const float4 b = *(const float4*)(gp + 4);
        bf16x8 h;
        h[0] = (short)f32_to_bf16_rne(a.x); h[1] = (short)f32_to_bf16_rne(a.y);
        h[2] = (short)f32_to_bf16_rne(a.z); h[3] = (short)f32_to_bf16_rne(a.w);
        h[4] = (short)f32_to_bf16_rne(b.x); h[5] = (short)f32_to_bf16_rne(b.y);
        h[6] = (short)f32_to_bf16_rne(b.z); h[7] = (short)f32_to_bf16_rne(b.w);
        *(bf16x8*)&featb[(size_t)i * 8] = h;
        uint2 q;
        q.x = fp8x4_pack(a.x, a.y, a.z, a.w);
        q.y = fp8x4_pack(b.x, b.y, b.z, b.w);
        *(uint2*)&feat8[(size_t)i * 8] = q;
    } else if (bid < FCONV_BLKS + WSPLIT_BLKS) {
        // ---- wsplit: W -> bf16 MFMA-fragment-linear layout ----
        const int unit = (bid - FCONV_BLKS) * 256 + t;
        if (unit >= 4096) return;
        const int phase = unit >> 11;        // 0..1
        const int kbi   = (unit >> 9) & 3;   // 0..3
        const int u     = unit & 511;
        const int j     = u & 127;
        const int c     = u >> 7;            // 0..3
        const float* __restrict__ W = phase ? Wneigh : Wself;
        const float* gp = &W[(size_t)j * D + kbi * 32 + c * 8];
        const int p = j >> 5, ks = c >> 1, g = c & 1;
        const size_t base = (size_t)(phase * 4 + kbi) * 4096
                          + (size_t)(((p * 2 + ks) * 64) + (j & 31) + 32 * g) * 8;
#pragma unroll
        for (int e = 0; e < 8; ++e)
            Wf[base + e] = f32_to_bf16_rne(gp[e]);
    } else {
        // ---- s1: per-wg bucket histogram ----
        const int w = bid - FCONV_BLKS - WSPLIT_BLKS;
        hist[t] = 0;
        __syncthreads();
        const int base = w * EPW;
        for (int i = t; i < EPW; i += 256)
            atomicAdd(&hist[dst[base + i] >> 8], 1);
        __syncthreads();
        ghist[w * 256 + t] = hist[t];
    }
}

// ---------------- S3 (with inline S2): scan ghist + bin edges packed ----------------
__launch_bounds__(256)
__global__ void s3_bin_kernel(const int* __restrict__ src,
                              const int* __restrict__ dst,
                              const int* __restrict__ ghist,
                              unsigned* __restrict__ binned,
                              int* __restrict__ gboff) {
    __shared__ int s[256];
    __shared__ int cur[256];
    const int t = threadIdx.x;
    const int w = blockIdx.x;
    int tot = 0, mypre = 0;
    for (int w2 = 0; w2 < NWG; ++w2) {
        const int v = ghist[w2 * 256 + t];
        tot += v;
        if (w2 < w) mypre += v;
    }
    s[t] = tot;
    __syncthreads();
    for (int d = 1; d < 256; d <<= 1) {
        int v = 0;
        if (t >= d) v = s[t - d];
        __syncthreads();
        s[t] += v;
        __syncthreads();
    }
    const int boff = s[t] - tot;   // exclusive bucket offset
    if (w == 0) {
        gboff[t] = boff;
        if (t == 255) gboff[256] = s[255];
    }
    cur[t] = boff + mypre;
    __syncthreads();
    const int base = w * EPW;
    for (int i = t; i < EPW; i += 256) {
        const int sv = src[base + i];
        const int d = dst[base + i];
        const int p = atomicAdd(&cur[d >> 8], 1);
        binned[p] = (unsigned)sv | ((unsigned)(d & 255) << 16);
    }
}

// ---------------- finalize: per-bucket degree + intra-bucket scan + CSR scatter ----------------
__launch_bounds__(256)
__global__ void finalize_kernel(const unsigned* __restrict__ binned,
                                const int* __restrict__ gboff,
                                int* __restrict__ deg_i,
                                int* __restrict__ off,
                                unsigned short* __restrict__ csr_src) {
    __shared__ int c0[256];
    __shared__ int s[256];
    __shared__ int cur[256];
    const int t = threadIdx.x;
    const int b = blockIdx.x;
    c0[t] = 0;
    __syncthreads();
    const int lo = gboff[b], hi = gboff[b + 1];
    for (int i = lo + t; i < hi; i += 256)
        atomicAdd(&c0[(binned[i] >> 16) & 255u], 1);
    __syncthreads();
    const int c = c0[t];
    s[t] = c;
    __syncthreads();
    for (int d = 1; d < 256; d <<= 1) {
        int v = 0;
        if (t >= d) v = s[t - d];
        __syncthreads();
        s[t] += v;
        __syncthreads();
    }
    const int o = gboff[b] + s[t] - c;   // global CSR offset for this node
    const int node = b * 256 + t;
    if (node < N_NODES) {
        deg_i[node] = c;
        off[node] = o;
    }
    cur[t] = o;
    __syncthreads();
    for (int i = lo + t; i < hi; i += 256) {
        const unsigned u = binned[i];
        const int p = atomicAdd(&cur[(u >> 16) & 255u], 1);
        csr_src[p] = (unsigned short)(u & 0xFFFFu);
    }
}

// ---------------- gather-aggregate: fp8 rows, 16 lanes/row, unroll 8, bf16 out ----------------
__launch_bounds__(256)
__global__ void gather_kernel(const unsigned char* __restrict__ feat8,
                              const int* __restrict__ off,
                              const int* __restrict__ deg_i,
                              const unsigned short* __restrict__ csr_src,
                              unsigned short* __restrict__ hneighb) {
    const int t = threadIdx.x;
    const int lane8 = (t & 15) * 8;                 // byte/feature base: 8 fp8 per lane
    const int node = blockIdx.x * 16 + (t >> 4);    // 16 nodes per 256-thread block
    if (node >= N_NODES) return;
    const int s0 = off[node];
    const int cnt = deg_i[node];
    const int end = s0 + cnt;
    float a0 = 0.f, a1 = 0.f, a2 = 0.f, a3 = 0.f;
    float a4 = 0.f, a5 = 0.f, a6 = 0.f, a7 = 0.f;
    int e = s0;
#define ACC(u) { const f32x2 p0 = fp8x2_lo((u).x); const f32x2 p1 = fp8x2_hi((u).x); \
                 const f32x2 p2 = fp8x2_lo((u).y); const f32x2 p3 = fp8x2_hi((u).y); \
                 a0 += p0.x; a1 += p0.y; a2 += p1.x; a3 += p1.y; \
                 a4 += p2.x; a5 += p2.y; a6 += p3.x; a7 += p3.y; }
    for (; e + 8 <= end; e += 8) {
        const int i0 = csr_src[e];
        const int i1 = csr_src[e + 1];
        const int i2 = csr_src[e + 2];
        const int i3 = csr_src[e + 3];
        const int i4 = csr_src[e + 4];
        const int i5 = csr_src[e + 5];
        const int i6 = csr_src[e + 6];
        const int i7 = csr_src[e + 7];
        const uint2 u0 = *(const uint2*)&feat8[(size_t)i0 * D + lane8];
        const uint2 u1 = *(const uint2*)&feat8[(size_t)i1 * D + lane8];
        const uint2 u2 = *(const uint2*)&feat8[(size_t)i2 * D + lane8];
        const uint2 u3 = *(const uint2*)&feat8[(size_t)i3 * D + lane8];
        const uint2 u4 = *(const uint2*)&feat8[(size_t)i4 * D + lane8];
        const uint2 u5 = *(const uint2*)&feat8[(size_t)i5 * D + lane8];
        const uint2 u6 = *(const uint2*)&feat8[(size_t)i6 * D + lane8];
        const uint2 u7 = *(const uint2*)&feat8[(size_t)i7 * D + lane8];
        ACC(u0); ACC(u1); ACC(u2); ACC(u3);
        ACC(u4); ACC(u5); ACC(u6); ACC(u7);
    }
    for (; e + 4 <= end; e += 4) {
        const int i0 = csr_src[e];
        const int i1 = csr_src[e + 1];
        const int i2 = csr_src[e + 2];
        const int i3 = csr_src[e + 3];
        const uint2 u0 = *(const uint2*)&feat8[(size_t)i0 * D + lane8];
        const uint2 u1 = *(const uint2*)&feat8[(size_t)i1 * D + lane8];
        const uint2 u2 = *(const uint2*)&feat8[(size_t)i2 * D + lane8];
        const uint2 u3 = *(const uint2*)&feat8[(size_t)i3 * D + lane8];
        ACC(u0); ACC(u1); ACC(u2); ACC(u3);
    }
    for (; e < end; ++e) {
        const uint2 u = *(const uint2*)&feat8[(size_t)csr_src[e] * D + lane8];
        ACC(u);
    }
#undef ACC
    const float sc = 1.f / fmaxf((float)cnt, 1.f);
    const unsigned h0 = f32_to_bf16_rne(a0 * sc);
    const unsigned h1 = f32_to_bf16_rne(a1 * sc);
    const unsigned h2 = f32_to_bf16_rne(a2 * sc);
    const unsigned h3 = f32_to_bf16_rne(a3 * sc);
    const unsigned h4 = f32_to_bf16_rne(a4 * sc);
    const unsigned h5 = f32_to_bf16_rne(a5 * sc);
    const unsigned h6 = f32_to_bf16_rne(a6 * sc);
    const unsigned h7 = f32_to_bf16_rne(a7 * sc);
    uint4 o;
    o.x = (h1 << 16) | h0;
    o.y = (h3 << 16) | h2;
    o.z = (h5 << 16) | h4;
    o.w = (h7 << 16) | h6;
    *(uint4*)&hneighb[(size_t)node * D + lane8] = o;
}

// ---------------- MFMA GEMM, pure bf16, W resident in LDS ----------------
__launch_bounds__(256)
__global__ void gemm_kernel(const unsigned short* __restrict__ featb,
                            const unsigned short* __restrict__ hneighb,
                            const unsigned short* __restrict__ Wf,
                            const float* __restrict__ bias,
                            float* __restrict__ out) {
    __shared__ __align__(16) unsigned short sW[32768];      // 64 KB: all 8 W chunks
    __shared__ __align__(16) unsigned short sA[2][4096];    // 2 x 8 KB A tiles

    const int tid  = threadIdx.x;
    const int wv   = tid >> 6;   // wave 0..3 -> A panel (rows wv*32..wv*32+31)
    const int l    = tid & 63;
    const int row0 = blockIdx.x * 128;

    // ---- load ALL of W once (64 KB, contiguous) ----
#pragma unroll
    for (int i = 0; i < 16; ++i) {
        const int o = (i * 256 + tid) * 8;
        *(bf16x8*)&sW[o] = *(const bf16x8*)&Wf[o];
    }

    auto stageA = [&](int sel, int blk) {
        const int kbi = blk & 3;
        const unsigned short* __restrict__ A = (blk < 4) ? featb : hneighb;
#pragma unroll
        for (int i = 0; i < 2; ++i) {
            const int u   = i * 256 + tid;   // 0..511 = 128 rows x 4 chunks
            const int row = u & 127;
            const int c   = u >> 7;          // 8-k chunk within the 32-k block
            const int grow = row0 + row;
            bf16x8 v = {};
            if (grow < N_NODES)
                v = *(const bf16x8*)&A[(size_t)grow * D + kbi * 32 + c * 8];
            const int p = row >> 5, ks = c >> 1, g = c & 1;
            const int o = ((p * 2 + ks) * 64 + (row & 31) + 32 * g) * 8;
            *(bf16x8*)&sA[sel][o] = v;
        }
    };

    f32x16 acc[4] = {};

    stageA(0, 0);
    __syncthreads();
#pragma unroll 1
    for (int blk = 0; blk < 8; ++blk) {
        const int cur = blk & 1;
        if (blk < 7) stageA(cur ^ 1, blk + 1);
        const int wbase = blk * 4096;
#pragma unroll
        for (int ks = 0; ks < 2; ++ks) {
            const bf16x8 a = *(const bf16x8*)&sA[cur][((wv * 2 + ks) * 64 + l) * 8];
#pragma unroll
            for (int n = 0; n < 4; ++n) {
                const bf16x8 w = *(const bf16x8*)&sW[wbase + ((n * 2 + ks) * 64 + l) * 8];
                acc[n] = __builtin_amdgcn_mfma_f32_32x32x16_bf16(a, w, acc[n], 0, 0, 0);
            }
        }
        __syncthreads();
    }

    // ---- epilogue: C/D layout col=l&31, row=(r&3)+8*(r>>2)+4*(l>>5) ----
    const int col = l & 31;
    const int hi2 = l >> 5;
    float bv[4];
#pragma unroll
    for (int n = 0; n < 4; ++n) bv[n] = bias[n * 32 + col];
#pragma unroll
    for (int r = 0; r < 16; ++r) {
        const int rloc = (r & 3) + 8 * (r >> 2) + 4 * hi2;
        const int grow = row0 + wv * 32 + rloc;
        if (grow < N_NODES) {
#pragma unroll
            for (int n = 0; n < 4; ++n)
                out[(size_t)grow * D + n * 32 + col] = acc[n][r] + bv[n];
        }
    }
}

extern "C" void kernel_launch(void* const* d_in, const int* in_sizes, int n_in,
                              void* d_out, int out_size, void* d_ws, size_t ws_size,
                              hipStream_t stream) {
    const float* feat  = (const float*)d_in[0];
    const float* Wn    = (const float*)d_in[1];  // W_neigh
    const float* Wsf   = (const float*)d_in[2];  // W_self
    const float* bself = (const float*)d_in[3];
    const int*   src   = (const int*)d_in[4];
    const int*   dst   = (const int*)d_in[5];
    float* out = (float*)d_out;

    // workspace layout (all sections keep 16B alignment)
    unsigned short* featb   = (unsigned short*)d_ws;               // N*D bf16
    unsigned short* hneighb = featb + (size_t)N_NODES * D;         // N*D bf16
    unsigned* binned = (unsigned*)(hneighb + (size_t)N_NODES * D); // E uint (packed)
    unsigned short* csr_src = (unsigned short*)(binned + N_EDGES); // E ushort
    int*   deg_i     = (int*)(csr_src + N_EDGES);                  // N ints
    int*   off       = deg_i + N_NODES;                            // N ints
    int*   ghist     = off + N_NODES;                              // NWG*256 ints
    int*   gboff     = ghist + NWG * 256;                          // 257 ints (pad 320)
    unsigned short* Wf = (unsigned short*)(gboff + 320);           // 8*4096 bf16
    unsigned char* feat8 = (unsigned char*)(Wf + 8 * 4096);        // N*D fp8

    prep_kernel<<<FCONV_BLKS + WSPLIT_BLKS + NWG, 256, 0, stream>>>(
        feat, Wsf, Wn, dst, featb, feat8, Wf, ghist);
    s3_bin_kernel<<<NWG, 256, 0, stream>>>(src, dst, ghist, binned, gboff);
    finalize_kernel<<<NBUCK, 256, 0, stream>>>(binned, gboff, deg_i, off, csr_src);
    gather_kernel<<<(N_NODES + 15) / 16, 256, 0, stream>>>(feat8, off, deg_i, csr_src, hneighb);

    const int gblocks = (N_NODES + 127) / 128;   // 391
    gemm_kernel<<<gblocks, 256, 0, stream>>>(featb, hneighb, Wf, bself, out);
}